// Round 12
// baseline (64.691 us; speedup 1.0000x reference)
//
#include <hip/hip_runtime.h>

// VAR flex-attention, MI355X gfx950. Mask == "q attends to keys [0, block_end(q))".
// R12: ZERO-SYNC main kernel. K/V fragments (bf16, pre-gathered by prepass)
// are read DIRECTLY from global into registers (L1/L2-resident; same-block
// waves share tiles). No LDS, no barriers, no vmcnt management, per-wave
// trip count (free load balance). Body = R10's fused mask+exp2+sum+cvt_pk
// softmax. 256-thr / 4-wave blocks, 64q/block, long-first XCD dispatch.

typedef float  f32x4 __attribute__((ext_vector_type(4)));
typedef short  s16x8 __attribute__((ext_vector_type(8)));
typedef short  s16x4 __attribute__((ext_vector_type(4)));
typedef unsigned int u32;
typedef u32    u32x4 __attribute__((ext_vector_type(4)));

#define L_TOK 680
#define LPAD  704
#define DHEAD 64
#define NBH   128
#define NTILE 11
#define SCALE_LOG2 0.18033688011112042f   // (1/8) * log2(e)

__device__ __forceinline__ int kv_len(int q) {
  return q < 1 ? 1 : q < 5 ? 5 : q < 14 ? 14 : q < 30 ? 30 : q < 55 ? 55
       : q < 91 ? 91 : q < 155 ? 155 : q < 255 ? 255 : q < 424 ? 424 : L_TOK;
}

__device__ __forceinline__ short f2bf(float x) {
  unsigned u = __float_as_uint(x);
  return (short)((u + 0x7FFFu + ((u >> 16) & 1u)) >> 16);
}

__device__ __forceinline__ s16x8 cvt8(f32x4 a, f32x4 b, float sc) {
  s16x8 f;
  f[0] = f2bf(a[0] * sc); f[1] = f2bf(a[1] * sc);
  f[2] = f2bf(a[2] * sc); f[3] = f2bf(a[3] * sc);
  f[4] = f2bf(b[0] * sc); f[5] = f2bf(b[1] * sc);
  f[6] = f2bf(b[2] * sc); f[7] = f2bf(b[3] * sc);
  return f;
}

__device__ __forceinline__ float exp2f_raw(float x) {
  float r; asm("v_exp_f32 %0, %1" : "=v"(r) : "v"(x)); return r;
}
__device__ __forceinline__ u32 cvtpk(float lo, float hi) {
  u32 r; asm("v_cvt_pk_bf16_f32 %0, %1, %2" : "=v"(r) : "v"(lo), "v"(hi)); return r;
}

__device__ __forceinline__ void gload16(const void* g, void* l) {
  __builtin_amdgcn_global_load_lds(
      (const __attribute__((address_space(1))) u32*)g,
      (__attribute__((address_space(3))) u32*)l, 16, 0, 0);
}

// ---- fused prepass (identical to R4..R11, proven) ---------------------------
__global__ __launch_bounds__(256) void prep_kv(
    const float* __restrict__ Kg, const float* __restrict__ Vg,
    short* __restrict__ Ks, short* __restrict__ Vt2)
{
  int b = blockIdx.x, tid = threadIdx.x;
  if (b < 2816) {
    int g = b * 256 + tid;
    int bh = g / (LPAD * 8);
    int rem = g - bh * (LPAD * 8);
    int r = rem >> 3, c = rem & 7;
    s16x8 o = (s16x8)0;
    if (r < L_TOK) {
      const float* src = Kg + ((size_t)(bh * L_TOK + r)) * DHEAD + c * 8;
      f32x4 a = *(const f32x4*)src;
      f32x4 bb = *(const f32x4*)(src + 4);
      o = cvt8(a, bb, 1.0f);
    }
    int cp = c ^ (r & 7);
    *(s16x8*)(Ks + ((size_t)(bh * LPAD + r)) * DHEAD + cp * 8) = o;
  } else {
    int bid = b - 2816;                       // bh*11 + t
    int bh = bid / NTILE, t = bid - bh * NTILE;
    int lg = tid & 3, l15 = (tid >> 2) & 15, dt = tid >> 6;
    int d = dt * 16 + l15;
    const float* vsrc = Vg + (size_t)bh * L_TOK * DHEAD + d;
    short* rowbase = Vt2 + ((size_t)(bh * NTILE + t)) * 4096 + d * 64;
    #pragma unroll
    for (int f = 0; f < 2; ++f) {
      short u[8];
      #pragma unroll
      for (int i = 0; i < 4; ++i) {
        int kv = t * 64 + f * 32 + lg * 4 + i;
        u[i]     = (kv < L_TOK)      ? f2bf(vsrc[(size_t)kv * DHEAD])        : (short)0;
        u[4 + i] = (kv + 16 < L_TOK) ? f2bf(vsrc[(size_t)(kv + 16) * DHEAD]) : (short)0;
      }
      int pos = (2 * lg + f) ^ (l15 & 7);
      *(s16x8*)(rowbase + pos * 8) = *(const s16x8*)u;
    }
  }
}

// ---- main kernel: zero-sync, register-direct K/V, per-wave trip count -------
__global__ __launch_bounds__(256, 4) void var_attn12(
    const float* __restrict__ Qg, const short* __restrict__ Ks,
    const short* __restrict__ Vt2, float* __restrict__ Og)
{
  const int tid  = threadIdx.x;
  const int lane = tid & 63, wave = tid >> 6;
  const int l15  = lane & 15, lg = lane >> 4;

  // dispatch: bid&7 -> XCD-stable bh-low (L2 reuse); long q-tiles first
  int bid  = blockIdx.x;                      // 0..1407
  int bhlo = bid & 7;
  int t_   = bid >> 3;                        // 0..175
  int bhhi = t_ / NTILE;
  int qbi  = t_ - bhhi * NTILE;
  int qb   = (NTILE - 1) - qbi;               // 10..0, long first
  int bh   = bhhi * 8 + bhlo;
  int qblk = qb * 64;

  const int qw        = qblk + wave * 16;     // may exceed L_TOK for last tile
  const int qc        = min(qw + l15, L_TOK - 1);
  const int my_kvlen  = kv_len(qc);
  const int kvmin_w   = kv_len(min(qw, L_TOK - 1));
  const int kv_need_w = (qw < L_TOK) ? kv_len(min(qw + 15, L_TOK - 1)) : 0;
  const int nt_w      = (kv_need_w + 63) >> 6;   // PER-WAVE trip count

  s16x8 qfrag[2];
  {
    const float* qp = Qg + ((size_t)(bh * L_TOK + qc)) * DHEAD + lg * 8;
    #pragma unroll
    for (int ks = 0; ks < 2; ++ks) {
      f32x4 a = *(const f32x4*)(qp + ks * 32);
      f32x4 b = *(const f32x4*)(qp + ks * 32 + 4);
      qfrag[ks] = cvt8(a, b, SCALE_LOG2);
    }
  }

  // per-lane global fragment base addresses (loop-invariant offsets)
  const int swz   = l15 & 7;
  const int koff0 = l15 * 128 + ((lg    ) ^ swz) * 16;
  const int koff1 = l15 * 128 + ((lg + 4) ^ swz) * 16;
  const int voff0 = l15 * 128 + ((2 * lg    ) ^ swz) * 16;
  const int voff1 = l15 * 128 + ((2 * lg + 1) ^ swz) * 16;

  const char* kpb = (const char*)(Ks  + (size_t)bh * LPAD * DHEAD);
  const char* vpb = (const char*)(Vt2 + (size_t)bh * NTILE * 4096);

  f32x4 oacc[4] = {};
  float l_run = 0.0f;

  for (int kt = 0; kt < nt_w; ++kt) {
    const int kv0 = kt * 64;
    const char* kb = kpb + (size_t)kt * 8192;   // 64 rows x 128B bf16 tile
    const char* vb = vpb + (size_t)kt * 8192;   // gathered V^T tile

    // QK^T (swapped): direct global fragment loads (L1/L2-hit)
    f32x4 sacc[4] = {};
    #pragma unroll
    for (int t16 = 0; t16 < 4; ++t16) {
      s16x8 kf0 = *(const s16x8*)(kb + t16 * 2048 + koff0);
      s16x8 kf1 = *(const s16x8*)(kb + t16 * 2048 + koff1);
      sacc[t16] = __builtin_amdgcn_mfma_f32_16x16x32_bf16(kf0, qfrag[0], sacc[t16], 0, 0, 0);
      sacc[t16] = __builtin_amdgcn_mfma_f32_16x16x32_bf16(kf1, qfrag[1], sacc[t16], 0, 0, 0);
    }

    // fused mask + fixed-max exp2 + sum + cvt_pk (register-cheap, R10-proven)
    u32x4 w0, w1;
    float lsum = 0.0f;
    if (kv0 + 64 <= kvmin_w) {                // wave-uniform full tile
      #pragma unroll
      for (int t16 = 0; t16 < 4; ++t16) {
        float a = exp2f_raw(sacc[t16][0]);
        float b = exp2f_raw(sacc[t16][1]);
        float c = exp2f_raw(sacc[t16][2]);
        float d = exp2f_raw(sacc[t16][3]);
        lsum += (a + b) + (c + d);
        u32 lo = cvtpk(a, b), hi = cvtpk(c, d);
        if (t16 < 2) { w0[2 * t16] = lo; w0[2 * t16 + 1] = hi; }
        else         { w1[2 * (t16 - 2)] = lo; w1[2 * (t16 - 2) + 1] = hi; }
      }
    } else {
      const int kbase = kv0 + lg * 4;
      #pragma unroll
      for (int t16 = 0; t16 < 4; ++t16) {
        float a = (kbase + t16 * 16     < my_kvlen) ? exp2f_raw(sacc[t16][0]) : 0.0f;
        float b = (kbase + t16 * 16 + 1 < my_kvlen) ? exp2f_raw(sacc[t16][1]) : 0.0f;
        float c = (kbase + t16 * 16 + 2 < my_kvlen) ? exp2f_raw(sacc[t16][2]) : 0.0f;
        float d = (kbase + t16 * 16 + 3 < my_kvlen) ? exp2f_raw(sacc[t16][3]) : 0.0f;
        lsum += (a + b) + (c + d);
        u32 lo = cvtpk(a, b), hi = cvtpk(c, d);
        if (t16 < 2) { w0[2 * t16] = lo; w0[2 * t16 + 1] = hi; }
        else         { w1[2 * (t16 - 2)] = lo; w1[2 * (t16 - 2) + 1] = hi; }
      }
    }
    l_run += lsum;
    s16x8 pf0 = __builtin_bit_cast(s16x8, w0);
    s16x8 pf1 = __builtin_bit_cast(s16x8, w1);

    // PV: direct global V-fragment loads
    #pragma unroll
    for (int dt = 0; dt < 4; ++dt) {
      s16x8 vf0 = *(const s16x8*)(vb + dt * 2048 + voff0);
      s16x8 vf1 = *(const s16x8*)(vb + dt * 2048 + voff1);
      oacc[dt] = __builtin_amdgcn_mfma_f32_16x16x32_bf16(pf0, vf0, oacc[dt], 0, 0, 0);
      oacc[dt] = __builtin_amdgcn_mfma_f32_16x16x32_bf16(pf1, vf1, oacc[dt], 0, 0, 0);
    }
  }

  // epilogue: reduce l across the 4 replica lane-groups, normalize, store
  l_run += __shfl_xor(l_run, 16);
  l_run += __shfl_xor(l_run, 32);
  float linv = 1.0f / l_run;
  float li_q[4];
  #pragma unroll
  for (int r = 0; r < 4; ++r) li_q[r] = __shfl(linv, lg * 4 + r);
  #pragma unroll
  for (int r = 0; r < 4; ++r) {
    int qo = qw + lg * 4 + r;
    if (qo < L_TOK) {
      float* dst = Og + ((size_t)(bh * L_TOK + qo)) * DHEAD + l15;
      #pragma unroll
      for (int dt = 0; dt < 4; ++dt) dst[dt * 16] = oacc[dt][r] * li_q[r];
    }
  }
}

// ---------------- R1 fallback kernel (f32 direct, no workspace) --------------
#define QBLK1  64
#define KVBLK1 32
#define VTS    36
__global__ __launch_bounds__(256, 2) void var_attn(
    const float* __restrict__ Qg, const float* __restrict__ Kg,
    const float* __restrict__ Vg, float* __restrict__ Og)
{
  const int tid  = threadIdx.x;
  const int bh   = blockIdx.y;
  const int qblk = blockIdx.x * QBLK1;
  const int wave = tid >> 6;
  const int lane = tid & 63;
  const int l15  = lane & 15;
  const int lg   = lane >> 4;

  __shared__ short kbuf[KVBLK1 * DHEAD];
  __shared__ short vtbuf[DHEAD * VTS];

  const int qw   = qblk + wave * 16;
  const int qc   = min(qw + l15, L_TOK - 1);
  const int my_kvlen  = kv_len(qc);
  const int kv_need_w = kv_len(min(qw + 15, L_TOK - 1));
  const int nkv       = kv_len(min(qblk + QBLK1 - 1, L_TOK - 1));

  s16x8 qfrag[2];
  {
    const float* qptr = Qg + ((size_t)(bh * L_TOK + qc)) * DHEAD + lg * 8;
    #pragma unroll
    for (int ks = 0; ks < 2; ++ks) {
      f32x4 a = *(const f32x4*)(qptr + ks * 32);
      f32x4 b = *(const f32x4*)(qptr + ks * 32 + 4);
      qfrag[ks] = cvt8(a, b, 0.125f);
    }
  }

  f32x4 oacc[4] = {};
  float m_run = -1e30f, l_run = 0.0f;

  const int stage_r = tid >> 3;
  const int stage_c = (tid & 7) * 8;
  const float* kbase = Kg + (size_t)bh * L_TOK * DHEAD;
  const float* vbase = Vg + (size_t)bh * L_TOK * DHEAD;

  for (int kv0 = 0; kv0 < nkv; kv0 += KVBLK1) {
    {
      const int rsrc = min(kv0 + stage_r, L_TOK - 1);
      const float* ks_ = kbase + (size_t)rsrc * DHEAD + stage_c;
      f32x4 a = *(const f32x4*)ks_;
      f32x4 b = *(const f32x4*)(ks_ + 4);
      s16x8 kf = cvt8(a, b, 1.0f);
      int boff = (stage_r * 128 + stage_c * 2) ^ ((stage_r & 7) << 4);
      *(s16x8*)((char*)kbuf + boff) = kf;
      const float* vs_ = vbase + (size_t)rsrc * DHEAD + stage_c;
      f32x4 c = *(const f32x4*)vs_;
      f32x4 d = *(const f32x4*)(vs_ + 4);
      #pragma unroll
      for (int i = 0; i < 4; ++i) vtbuf[(stage_c + i) * VTS + stage_r] = f2bf(c[i]);
      #pragma unroll
      for (int i = 0; i < 4; ++i) vtbuf[(stage_c + 4 + i) * VTS + stage_r] = f2bf(d[i]);
    }
    __syncthreads();
    if (kv0 < kv_need_w) {
      f32x4 sacc[2] = {};
      #pragma unroll
      for (int t = 0; t < 2; ++t) {
        const int kr = t * 16 + l15;
        #pragma unroll
        for (int ks = 0; ks < 2; ++ks) {
          int boff = (kr * 128 + (lg * 8 + ks * 32) * 2) ^ ((kr & 7) << 4);
          s16x8 kf = *(const s16x8*)((char*)kbuf + boff);
          sacc[t] = __builtin_amdgcn_mfma_f32_16x16x32_bf16(kf, qfrag[ks], sacc[t], 0, 0, 0);
        }
      }
      float s[8];
      #pragma unroll
      for (int t = 0; t < 2; ++t)
        #pragma unroll
        for (int r = 0; r < 4; ++r) {
          int key = kv0 + t * 16 + lg * 4 + r;
          s[t * 4 + r] = (key < my_kvlen) ? sacc[t][r] : -1e30f;
        }
      float mt = s[0];
      #pragma unroll
      for (int i = 1; i < 8; ++i) mt = fmaxf(mt, s[i]);
      mt = fmaxf(mt, __shfl_xor(mt, 16));
      mt = fmaxf(mt, __shfl_xor(mt, 32));
      float m_new = fmaxf(m_run, mt);
      float sc = __expf(m_run - m_new);
      float psum = 0.0f;
      short pf[8];
      #pragma unroll
      for (int i = 0; i < 8; ++i) {
        float pp = __expf(s[i] - m_new);
        psum += pp;
        pf[i] = f2bf(pp);
      }
      psum += __shfl_xor(psum, 16);
      psum += __shfl_xor(psum, 32);
      l_run = l_run * sc + psum;
      m_run = m_new;
      float sc_q[4];
      #pragma unroll
      for (int r = 0; r < 4; ++r) sc_q[r] = __shfl(sc, lg * 4 + r);
      #pragma unroll
      for (int dt = 0; dt < 4; ++dt)
        #pragma unroll
        for (int r = 0; r < 4; ++r) oacc[dt][r] *= sc_q[r];
      s16x8 pfrag;
      #pragma unroll
      for (int i = 0; i < 8; ++i) pfrag[i] = pf[i];
      #pragma unroll
      for (int dt = 0; dt < 4; ++dt) {
        const short* row = vtbuf + (dt * 16 + l15) * VTS + lg * 4;
        s16x4 v0 = *(const s16x4*)row;
        s16x4 v1 = *(const s16x4*)(row + 16);
        s16x8 vf;
        vf[0] = v0[0]; vf[1] = v0[1]; vf[2] = v0[2]; vf[3] = v0[3];
        vf[4] = v1[0]; vf[5] = v1[1]; vf[6] = v1[2]; vf[7] = v1[3];
        oacc[dt] = __builtin_amdgcn_mfma_f32_16x16x32_bf16(pfrag, vf, oacc[dt], 0, 0, 0);
      }
    }
    __syncthreads();
  }

  float linv = 1.0f / l_run;
  float li_q[4];
  #pragma unroll
  for (int r = 0; r < 4; ++r) li_q[r] = __shfl(linv, lg * 4 + r);
  #pragma unroll
  for (int r = 0; r < 4; ++r) {
    int qo = qw + lg * 4 + r;
    if (qo < L_TOK) {
      float* dst = Og + ((size_t)(bh * L_TOK + qo)) * DHEAD + l15;
      #pragma unroll
      for (int dt = 0; dt < 4; ++dt) dst[dt * 16] = oacc[dt][r] * li_q[r];
    }
  }
}

extern "C" void kernel_launch(void* const* d_in, const int* in_sizes, int n_in,
                              void* d_out, int out_size, void* d_ws, size_t ws_size,
                              hipStream_t stream) {
  const float* q = (const float*)d_in[0];
  const float* k = (const float*)d_in[1];
  const float* v = (const float*)d_in[2];
  float* o = (float*)d_out;

  const size_t ksz  = (size_t)NBH * LPAD * DHEAD;     // shorts (= Vt2 size too)
  const size_t need = 2 * ksz * sizeof(short);        // 23.1 MB
  if (ws_size >= need) {
    short* Ks  = (short*)d_ws;
    short* Vt2 = Ks + ksz;
    prep_kv<<<4224, 256, 0, stream>>>(k, v, Ks, Vt2);
    var_attn12<<<1408, 256, 0, stream>>>(q, Ks, Vt2, o);
  } else {
    dim3 grid((L_TOK + QBLK1 - 1) / QBLK1, NBH);
    var_attn<<<grid, 256, 0, stream>>>(q, k, v, o);
  }
}

// Round 13
// 64.415 us; speedup vs baseline: 1.0043x; 1.0043x over previous
//
#include <hip/hip_runtime.h>

// VAR flex-attention, MI355X gfx950. Mask == "q attends to keys [0, block_end(q))".
// R12: ZERO-SYNC main kernel. K/V fragments (bf16, pre-gathered by prepass)
// are read DIRECTLY from global into registers (L1/L2-resident; same-block
// waves share tiles). No LDS, no barriers, no vmcnt management, per-wave
// trip count (free load balance). Body = R10's fused mask+exp2+sum+cvt_pk
// softmax. 256-thr / 4-wave blocks, 64q/block, long-first XCD dispatch.

typedef float  f32x4 __attribute__((ext_vector_type(4)));
typedef short  s16x8 __attribute__((ext_vector_type(8)));
typedef short  s16x4 __attribute__((ext_vector_type(4)));
typedef unsigned int u32;
typedef u32    u32x4 __attribute__((ext_vector_type(4)));

#define L_TOK 680
#define LPAD  704
#define DHEAD 64
#define NBH   128
#define NTILE 11
#define SCALE_LOG2 0.18033688011112042f   // (1/8) * log2(e)

__device__ __forceinline__ int kv_len(int q) {
  return q < 1 ? 1 : q < 5 ? 5 : q < 14 ? 14 : q < 30 ? 30 : q < 55 ? 55
       : q < 91 ? 91 : q < 155 ? 155 : q < 255 ? 255 : q < 424 ? 424 : L_TOK;
}

__device__ __forceinline__ short f2bf(float x) {
  unsigned u = __float_as_uint(x);
  return (short)((u + 0x7FFFu + ((u >> 16) & 1u)) >> 16);
}

__device__ __forceinline__ s16x8 cvt8(f32x4 a, f32x4 b, float sc) {
  s16x8 f;
  f[0] = f2bf(a[0] * sc); f[1] = f2bf(a[1] * sc);
  f[2] = f2bf(a[2] * sc); f[3] = f2bf(a[3] * sc);
  f[4] = f2bf(b[0] * sc); f[5] = f2bf(b[1] * sc);
  f[6] = f2bf(b[2] * sc); f[7] = f2bf(b[3] * sc);
  return f;
}

__device__ __forceinline__ float exp2f_raw(float x) {
  float r; asm("v_exp_f32 %0, %1" : "=v"(r) : "v"(x)); return r;
}
__device__ __forceinline__ u32 cvtpk(float lo, float hi) {
  u32 r; asm("v_cvt_pk_bf16_f32 %0, %1, %2" : "=v"(r) : "v"(lo), "v"(hi)); return r;
}

__device__ __forceinline__ void gload16(const void* g, void* l) {
  __builtin_amdgcn_global_load_lds(
      (const __attribute__((address_space(1))) u32*)g,
      (__attribute__((address_space(3))) u32*)l, 16, 0, 0);
}

// ---- fused prepass (identical to R4..R11, proven) ---------------------------
__global__ __launch_bounds__(256) void prep_kv(
    const float* __restrict__ Kg, const float* __restrict__ Vg,
    short* __restrict__ Ks, short* __restrict__ Vt2)
{
  int b = blockIdx.x, tid = threadIdx.x;
  if (b < 2816) {
    int g = b * 256 + tid;
    int bh = g / (LPAD * 8);
    int rem = g - bh * (LPAD * 8);
    int r = rem >> 3, c = rem & 7;
    s16x8 o = (s16x8)0;
    if (r < L_TOK) {
      const float* src = Kg + ((size_t)(bh * L_TOK + r)) * DHEAD + c * 8;
      f32x4 a = *(const f32x4*)src;
      f32x4 bb = *(const f32x4*)(src + 4);
      o = cvt8(a, bb, 1.0f);
    }
    int cp = c ^ (r & 7);
    *(s16x8*)(Ks + ((size_t)(bh * LPAD + r)) * DHEAD + cp * 8) = o;
  } else {
    int bid = b - 2816;                       // bh*11 + t
    int bh = bid / NTILE, t = bid - bh * NTILE;
    int lg = tid & 3, l15 = (tid >> 2) & 15, dt = tid >> 6;
    int d = dt * 16 + l15;
    const float* vsrc = Vg + (size_t)bh * L_TOK * DHEAD + d;
    short* rowbase = Vt2 + ((size_t)(bh * NTILE + t)) * 4096 + d * 64;
    #pragma unroll
    for (int f = 0; f < 2; ++f) {
      short u[8];
      #pragma unroll
      for (int i = 0; i < 4; ++i) {
        int kv = t * 64 + f * 32 + lg * 4 + i;
        u[i]     = (kv < L_TOK)      ? f2bf(vsrc[(size_t)kv * DHEAD])        : (short)0;
        u[4 + i] = (kv + 16 < L_TOK) ? f2bf(vsrc[(size_t)(kv + 16) * DHEAD]) : (short)0;
      }
      int pos = (2 * lg + f) ^ (l15 & 7);
      *(s16x8*)(rowbase + pos * 8) = *(const s16x8*)u;
    }
  }
}

// ---- main kernel: zero-sync, register-direct K/V, per-wave trip count -------
__global__ __launch_bounds__(256, 4) void var_attn12(
    const float* __restrict__ Qg, const short* __restrict__ Ks,
    const short* __restrict__ Vt2, float* __restrict__ Og)
{
  const int tid  = threadIdx.x;
  const int lane = tid & 63, wave = tid >> 6;
  const int l15  = lane & 15, lg = lane >> 4;

  // dispatch: bid&7 -> XCD-stable bh-low (L2 reuse); long q-tiles first
  int bid  = blockIdx.x;                      // 0..1407
  int bhlo = bid & 7;
  int t_   = bid >> 3;                        // 0..175
  int bhhi = t_ / NTILE;
  int qbi  = t_ - bhhi * NTILE;
  int qb   = (NTILE - 1) - qbi;               // 10..0, long first
  int bh   = bhhi * 8 + bhlo;
  int qblk = qb * 64;

  const int qw        = qblk + wave * 16;     // may exceed L_TOK for last tile
  const int qc        = min(qw + l15, L_TOK - 1);
  const int my_kvlen  = kv_len(qc);
  const int kvmin_w   = kv_len(min(qw, L_TOK - 1));
  const int kv_need_w = (qw < L_TOK) ? kv_len(min(qw + 15, L_TOK - 1)) : 0;
  const int nt_w      = (kv_need_w + 63) >> 6;   // PER-WAVE trip count

  s16x8 qfrag[2];
  {
    const float* qp = Qg + ((size_t)(bh * L_TOK + qc)) * DHEAD + lg * 8;
    #pragma unroll
    for (int ks = 0; ks < 2; ++ks) {
      f32x4 a = *(const f32x4*)(qp + ks * 32);
      f32x4 b = *(const f32x4*)(qp + ks * 32 + 4);
      qfrag[ks] = cvt8(a, b, SCALE_LOG2);
    }
  }

  // per-lane global fragment base addresses (loop-invariant offsets)
  const int swz   = l15 & 7;
  const int koff0 = l15 * 128 + ((lg    ) ^ swz) * 16;
  const int koff1 = l15 * 128 + ((lg + 4) ^ swz) * 16;
  const int voff0 = l15 * 128 + ((2 * lg    ) ^ swz) * 16;
  const int voff1 = l15 * 128 + ((2 * lg + 1) ^ swz) * 16;

  const char* kpb = (const char*)(Ks  + (size_t)bh * LPAD * DHEAD);
  const char* vpb = (const char*)(Vt2 + (size_t)bh * NTILE * 4096);

  f32x4 oacc[4] = {};
  float l_run = 0.0f;

  for (int kt = 0; kt < nt_w; ++kt) {
    const int kv0 = kt * 64;
    const char* kb = kpb + (size_t)kt * 8192;   // 64 rows x 128B bf16 tile
    const char* vb = vpb + (size_t)kt * 8192;   // gathered V^T tile

    // QK^T (swapped): direct global fragment loads (L1/L2-hit)
    f32x4 sacc[4] = {};
    #pragma unroll
    for (int t16 = 0; t16 < 4; ++t16) {
      s16x8 kf0 = *(const s16x8*)(kb + t16 * 2048 + koff0);
      s16x8 kf1 = *(const s16x8*)(kb + t16 * 2048 + koff1);
      sacc[t16] = __builtin_amdgcn_mfma_f32_16x16x32_bf16(kf0, qfrag[0], sacc[t16], 0, 0, 0);
      sacc[t16] = __builtin_amdgcn_mfma_f32_16x16x32_bf16(kf1, qfrag[1], sacc[t16], 0, 0, 0);
    }

    // fused mask + fixed-max exp2 + sum + cvt_pk (register-cheap, R10-proven)
    u32x4 w0, w1;
    float lsum = 0.0f;
    if (kv0 + 64 <= kvmin_w) {                // wave-uniform full tile
      #pragma unroll
      for (int t16 = 0; t16 < 4; ++t16) {
        float a = exp2f_raw(sacc[t16][0]);
        float b = exp2f_raw(sacc[t16][1]);
        float c = exp2f_raw(sacc[t16][2]);
        float d = exp2f_raw(sacc[t16][3]);
        lsum += (a + b) + (c + d);
        u32 lo = cvtpk(a, b), hi = cvtpk(c, d);
        if (t16 < 2) { w0[2 * t16] = lo; w0[2 * t16 + 1] = hi; }
        else         { w1[2 * (t16 - 2)] = lo; w1[2 * (t16 - 2) + 1] = hi; }
      }
    } else {
      const int kbase = kv0 + lg * 4;
      #pragma unroll
      for (int t16 = 0; t16 < 4; ++t16) {
        float a = (kbase + t16 * 16     < my_kvlen) ? exp2f_raw(sacc[t16][0]) : 0.0f;
        float b = (kbase + t16 * 16 + 1 < my_kvlen) ? exp2f_raw(sacc[t16][1]) : 0.0f;
        float c = (kbase + t16 * 16 + 2 < my_kvlen) ? exp2f_raw(sacc[t16][2]) : 0.0f;
        float d = (kbase + t16 * 16 + 3 < my_kvlen) ? exp2f_raw(sacc[t16][3]) : 0.0f;
        lsum += (a + b) + (c + d);
        u32 lo = cvtpk(a, b), hi = cvtpk(c, d);
        if (t16 < 2) { w0[2 * t16] = lo; w0[2 * t16 + 1] = hi; }
        else         { w1[2 * (t16 - 2)] = lo; w1[2 * (t16 - 2) + 1] = hi; }
      }
    }
    l_run += lsum;
    s16x8 pf0 = __builtin_bit_cast(s16x8, w0);
    s16x8 pf1 = __builtin_bit_cast(s16x8, w1);

    // PV: direct global V-fragment loads
    #pragma unroll
    for (int dt = 0; dt < 4; ++dt) {
      s16x8 vf0 = *(const s16x8*)(vb + dt * 2048 + voff0);
      s16x8 vf1 = *(const s16x8*)(vb + dt * 2048 + voff1);
      oacc[dt] = __builtin_amdgcn_mfma_f32_16x16x32_bf16(pf0, vf0, oacc[dt], 0, 0, 0);
      oacc[dt] = __builtin_amdgcn_mfma_f32_16x16x32_bf16(pf1, vf1, oacc[dt], 0, 0, 0);
    }
  }

  // epilogue: reduce l across the 4 replica lane-groups, normalize, store
  l_run += __shfl_xor(l_run, 16);
  l_run += __shfl_xor(l_run, 32);
  float linv = 1.0f / l_run;
  float li_q[4];
  #pragma unroll
  for (int r = 0; r < 4; ++r) li_q[r] = __shfl(linv, lg * 4 + r);
  #pragma unroll
  for (int r = 0; r < 4; ++r) {
    int qo = qw + lg * 4 + r;
    if (qo < L_TOK) {
      float* dst = Og + ((size_t)(bh * L_TOK + qo)) * DHEAD + l15;
      #pragma unroll
      for (int dt = 0; dt < 4; ++dt) dst[dt * 16] = oacc[dt][r] * li_q[r];
    }
  }
}

// ---------------- R1 fallback kernel (f32 direct, no workspace) --------------
#define QBLK1  64
#define KVBLK1 32
#define VTS    36
__global__ __launch_bounds__(256, 2) void var_attn(
    const float* __restrict__ Qg, const float* __restrict__ Kg,
    const float* __restrict__ Vg, float* __restrict__ Og)
{
  const int tid  = threadIdx.x;
  const int bh   = blockIdx.y;
  const int qblk = blockIdx.x * QBLK1;
  const int wave = tid >> 6;
  const int lane = tid & 63;
  const int l15  = lane & 15;
  const int lg   = lane >> 4;

  __shared__ short kbuf[KVBLK1 * DHEAD];
  __shared__ short vtbuf[DHEAD * VTS];

  const int qw   = qblk + wave * 16;
  const int qc   = min(qw + l15, L_TOK - 1);
  const int my_kvlen  = kv_len(qc);
  const int kv_need_w = kv_len(min(qw + 15, L_TOK - 1));
  const int nkv       = kv_len(min(qblk + QBLK1 - 1, L_TOK - 1));

  s16x8 qfrag[2];
  {
    const float* qptr = Qg + ((size_t)(bh * L_TOK + qc)) * DHEAD + lg * 8;
    #pragma unroll
    for (int ks = 0; ks < 2; ++ks) {
      f32x4 a = *(const f32x4*)(qptr + ks * 32);
      f32x4 b = *(const f32x4*)(qptr + ks * 32 + 4);
      qfrag[ks] = cvt8(a, b, 0.125f);
    }
  }

  f32x4 oacc[4] = {};
  float m_run = -1e30f, l_run = 0.0f;

  const int stage_r = tid >> 3;
  const int stage_c = (tid & 7) * 8;
  const float* kbase = Kg + (size_t)bh * L_TOK * DHEAD;
  const float* vbase = Vg + (size_t)bh * L_TOK * DHEAD;

  for (int kv0 = 0; kv0 < nkv; kv0 += KVBLK1) {
    {
      const int rsrc = min(kv0 + stage_r, L_TOK - 1);
      const float* ks_ = kbase + (size_t)rsrc * DHEAD + stage_c;
      f32x4 a = *(const f32x4*)ks_;
      f32x4 b = *(const f32x4*)(ks_ + 4);
      s16x8 kf = cvt8(a, b, 1.0f);
      int boff = (stage_r * 128 + stage_c * 2) ^ ((stage_r & 7) << 4);
      *(s16x8*)((char*)kbuf + boff) = kf;
      const float* vs_ = vbase + (size_t)rsrc * DHEAD + stage_c;
      f32x4 c = *(const f32x4*)vs_;
      f32x4 d = *(const f32x4*)(vs_ + 4);
      #pragma unroll
      for (int i = 0; i < 4; ++i) vtbuf[(stage_c + i) * VTS + stage_r] = f2bf(c[i]);
      #pragma unroll
      for (int i = 0; i < 4; ++i) vtbuf[(stage_c + 4 + i) * VTS + stage_r] = f2bf(d[i]);
    }
    __syncthreads();
    if (kv0 < kv_need_w) {
      f32x4 sacc[2] = {};
      #pragma unroll
      for (int t = 0; t < 2; ++t) {
        const int kr = t * 16 + l15;
        #pragma unroll
        for (int ks = 0; ks < 2; ++ks) {
          int boff = (kr * 128 + (lg * 8 + ks * 32) * 2) ^ ((kr & 7) << 4);
          s16x8 kf = *(const s16x8*)((char*)kbuf + boff);
          sacc[t] = __builtin_amdgcn_mfma_f32_16x16x32_bf16(kf, qfrag[ks], sacc[t], 0, 0, 0);
        }
      }
      float s[8];
      #pragma unroll
      for (int t = 0; t < 2; ++t)
        #pragma unroll
        for (int r = 0; r < 4; ++r) {
          int key = kv0 + t * 16 + lg * 4 + r;
          s[t * 4 + r] = (key < my_kvlen) ? sacc[t][r] : -1e30f;
        }
      float mt = s[0];
      #pragma unroll
      for (int i = 1; i < 8; ++i) mt = fmaxf(mt, s[i]);
      mt = fmaxf(mt, __shfl_xor(mt, 16));
      mt = fmaxf(mt, __shfl_xor(mt, 32));
      float m_new = fmaxf(m_run, mt);
      float sc = __expf(m_run - m_new);
      float psum = 0.0f;
      short pf[8];
      #pragma unroll
      for (int i = 0; i < 8; ++i) {
        float pp = __expf(s[i] - m_new);
        psum += pp;
        pf[i] = f2bf(pp);
      }
      psum += __shfl_xor(psum, 16);
      psum += __shfl_xor(psum, 32);
      l_run = l_run * sc + psum;
      m_run = m_new;
      float sc_q[4];
      #pragma unroll
      for (int r = 0; r < 4; ++r) sc_q[r] = __shfl(sc, lg * 4 + r);
      #pragma unroll
      for (int dt = 0; dt < 4; ++dt)
        #pragma unroll
        for (int r = 0; r < 4; ++r) oacc[dt][r] *= sc_q[r];
      s16x8 pfrag;
      #pragma unroll
      for (int i = 0; i < 8; ++i) pfrag[i] = pf[i];
      #pragma unroll
      for (int dt = 0; dt < 4; ++dt) {
        const short* row = vtbuf + (dt * 16 + l15) * VTS + lg * 4;
        s16x4 v0 = *(const s16x4*)row;
        s16x4 v1 = *(const s16x4*)(row + 16);
        s16x8 vf;
        vf[0] = v0[0]; vf[1] = v0[1]; vf[2] = v0[2]; vf[3] = v0[3];
        vf[4] = v1[0]; vf[5] = v1[1]; vf[6] = v1[2]; vf[7] = v1[3];
        oacc[dt] = __builtin_amdgcn_mfma_f32_16x16x32_bf16(pfrag, vf, oacc[dt], 0, 0, 0);
      }
    }
    __syncthreads();
  }

  float linv = 1.0f / l_run;
  float li_q[4];
  #pragma unroll
  for (int r = 0; r < 4; ++r) li_q[r] = __shfl(linv, lg * 4 + r);
  #pragma unroll
  for (int r = 0; r < 4; ++r) {
    int qo = qw + lg * 4 + r;
    if (qo < L_TOK) {
      float* dst = Og + ((size_t)(bh * L_TOK + qo)) * DHEAD + l15;
      #pragma unroll
      for (int dt = 0; dt < 4; ++dt) dst[dt * 16] = oacc[dt][r] * li_q[r];
    }
  }
}

extern "C" void kernel_launch(void* const* d_in, const int* in_sizes, int n_in,
                              void* d_out, int out_size, void* d_ws, size_t ws_size,
                              hipStream_t stream) {
  const float* q = (const float*)d_in[0];
  const float* k = (const float*)d_in[1];
  const float* v = (const float*)d_in[2];
  float* o = (float*)d_out;

  const size_t ksz  = (size_t)NBH * LPAD * DHEAD;     // shorts (= Vt2 size too)
  const size_t need = 2 * ksz * sizeof(short);        // 23.1 MB
  if (ws_size >= need) {
    short* Ks  = (short*)d_ws;
    short* Vt2 = Ks + ksz;
    prep_kv<<<4224, 256, 0, stream>>>(k, v, Ks, Vt2);
    var_attn12<<<1408, 256, 0, stream>>>(q, Ks, Vt2, o);
  } else {
    dim3 grid((L_TOK + QBLK1 - 1) / QBLK1, NBH);
    var_attn<<<grid, 256, 0, stream>>>(q, k, v, o);
  }
}

// Round 14
// 38.168 us; speedup vs baseline: 1.6949x; 1.6877x over previous
//
#include <hip/hip_runtime.h>

// VAR flex-attention, MI355X gfx950. Mask == "q attends to keys [0, block_end(q))".
// R13: SINGLE-KERNEL — prepass eliminated. Each block stages its 64-kv K/V
// tile in-kernel: f32 global loads -> regs (issued at top of compute, one full
// phase of latency slack), cvt_pk_bf16 -> ds_write_b128 into the proven
// swizzled K / gathered-V^T LDS layouts, double-buffered, 2 barriers/iter.
// Compute body = R10 (fused mask+exp2+sum+cvt_pk fixed-max softmax, setprio).
// 512-thr / 8-wave blocks, QBLK=128, long-first XCD dispatch. No workspace.

typedef float  f32x4 __attribute__((ext_vector_type(4)));
typedef short  s16x8 __attribute__((ext_vector_type(8)));
typedef unsigned int u32;
typedef u32    u32x4 __attribute__((ext_vector_type(4)));

#define L_TOK 680
#define DHEAD 64
#define NBH   128
#define SCALE_LOG2 0.18033688011112042f   // (1/8) * log2(e)

__device__ __forceinline__ int kv_len(int q) {
  return q < 1 ? 1 : q < 5 ? 5 : q < 14 ? 14 : q < 30 ? 30 : q < 55 ? 55
       : q < 91 ? 91 : q < 155 ? 155 : q < 255 ? 255 : q < 424 ? 424 : L_TOK;
}

__device__ __forceinline__ short f2bf(float x) {
  unsigned u = __float_as_uint(x);
  return (short)((u + 0x7FFFu + ((u >> 16) & 1u)) >> 16);
}

__device__ __forceinline__ s16x8 cvt8(f32x4 a, f32x4 b, float sc) {
  s16x8 f;
  f[0] = f2bf(a[0] * sc); f[1] = f2bf(a[1] * sc);
  f[2] = f2bf(a[2] * sc); f[3] = f2bf(a[3] * sc);
  f[4] = f2bf(b[0] * sc); f[5] = f2bf(b[1] * sc);
  f[6] = f2bf(b[2] * sc); f[7] = f2bf(b[3] * sc);
  return f;
}

__device__ __forceinline__ float exp2f_raw(float x) {
  float r; asm("v_exp_f32 %0, %1" : "=v"(r) : "v"(x)); return r;
}
__device__ __forceinline__ u32 cvtpk(float lo, float hi) {
  u32 r; asm("v_cvt_pk_bf16_f32 %0, %1, %2" : "=v"(r) : "v"(lo), "v"(hi)); return r;
}

// ---- main (and only) kernel: 8 waves x 16q = 128q/block, 64-kv tiles -------
__global__ __launch_bounds__(512, 6) void var_attn13(
    const float* __restrict__ Qg, const float* __restrict__ Kg,
    const float* __restrict__ Vg, float* __restrict__ Og)
{
  const int tid  = threadIdx.x;
  const int lane = tid & 63, wave = tid >> 6;
  const int l15  = lane & 15, lg = lane >> 4;

  // dispatch: bid&7 -> XCD-stable bh-low (L2 reuse); long q-tiles first
  int bid  = blockIdx.x;                      // 0..767
  int bhlo = bid & 7;
  int t_   = bid >> 3;                        // 0..95
  int qbi  = t_ >> 4;                         // 0..5
  int bhhi = t_ & 15;
  int qb2  = (qbi < 3) ? (qbi + 3) : (5 - qbi);   // 3,4,5,2,1,0 (nt 11,11,11,7,4,3)
  int bh   = bhhi * 8 + bhlo;
  int qblk = qb2 * 128;

  __shared__ short kbuf[2][64 * DHEAD];       // 2 x 8KB, chunk16 ^ (r&7)
  __shared__ short vbuf[2][64 * DHEAD];       // 2 x 8KB, gathered V^T fragments

  const int qw        = qblk + wave * 16;
  const int qc        = min(qw + l15, L_TOK - 1);
  const int my_kvlen  = kv_len(qc);
  const int kvmin_w   = kv_len(min(qw, L_TOK - 1));
  const int kv_need_w = (qw < L_TOK) ? kv_len(min(qw + 15, L_TOK - 1)) : 0;
  const int nkv       = kv_len(min(qblk + 127, L_TOK - 1));
  const int nt        = (nkv + 63) >> 6;      // 3,4,7,11,11,11

  s16x8 qfrag[2];
  {
    const float* qp = Qg + ((size_t)(bh * L_TOK + qc)) * DHEAD + lg * 8;
    #pragma unroll
    for (int ks = 0; ks < 2; ++ks) {
      f32x4 a = *(const f32x4*)(qp + ks * 32);
      f32x4 b = *(const f32x4*)(qp + ks * 32 + 4);
      qfrag[ks] = cvt8(a, b, SCALE_LOG2);
    }
  }

  const float* kbase = Kg + (size_t)bh * L_TOK * DHEAD;
  const float* vbase = Vg + (size_t)bh * L_TOK * DHEAD;

  // ---- staging thread roles (per 64x64 tile) ----
  // K: thread -> row kr_s = tid>>3 (0..63), chunk kc_s = tid&7 (8 f32)
  const int kr_s = tid >> 3, kc_s = tid & 7;
  // V: thread -> d vd_s = tid&63, group: lg_s = (tid>>6)&3, f_s = tid>>8
  const int vd_s = tid & 63, lg_s = (tid >> 6) & 3, f_s = tid >> 8;

  // staged f32 regs (live across one compute phase)
  f32x4 kA, kB;
  float vA[8];

  auto loadregs = [&](int kt) {
    const int kv0 = kt * 64;
    const float* kp = kbase + (size_t)min(kv0 + kr_s, L_TOK - 1) * DHEAD + kc_s * 8;
    kA = *(const f32x4*)kp;
    kB = *(const f32x4*)(kp + 4);
    #pragma unroll
    for (int i = 0; i < 4; ++i) {
      int kv  = kv0 + f_s * 32 + lg_s * 4 + i;
      vA[i]     = vbase[(size_t)min(kv,      L_TOK - 1) * DHEAD + vd_s];
      vA[4 + i] = vbase[(size_t)min(kv + 16, L_TOK - 1) * DHEAD + vd_s];
    }
  };

  auto writelds = [&](int buf) {
    // K: convert 8 f32 -> s16x8, write at swizzled chunk
    u32x4 kw;
    kw[0] = cvtpk(kA[0], kA[1]); kw[1] = cvtpk(kA[2], kA[3]);
    kw[2] = cvtpk(kB[0], kB[1]); kw[3] = cvtpk(kB[2], kB[3]);
    *(u32x4*)(&kbuf[buf][kr_s * 64 + ((kc_s ^ (kr_s & 7)) * 8)]) = kw;
    // V: gathered fragment, write at swizzled pos
    u32x4 vw;
    vw[0] = cvtpk(vA[0], vA[1]); vw[1] = cvtpk(vA[2], vA[3]);
    vw[2] = cvtpk(vA[4], vA[5]); vw[3] = cvtpk(vA[6], vA[7]);
    int pos = (2 * lg_s + f_s) ^ (vd_s & 7);
    *(u32x4*)(&vbuf[buf][vd_s * 64 + pos * 8]) = vw;
  };

  // hoisted loop-invariant LDS byte offsets (compute phase)
  const int swz   = l15 & 7;
  const int koff0 = l15 * 128 + ((lg    ) ^ swz) * 16;
  const int koff1 = l15 * 128 + ((lg + 4) ^ swz) * 16;
  const int voff0 = l15 * 128 + ((2 * lg    ) ^ swz) * 16;
  const int voff1 = l15 * 128 + ((2 * lg + 1) ^ swz) * 16;

  f32x4 oacc[4] = {};
  float l_run = 0.0f;

  // prologue: stage tile 0
  loadregs(0);
  writelds(0);
  __syncthreads();

  for (int kt = 0; kt < nt; ++kt) {
    if (kt + 1 < nt) loadregs(kt + 1);        // issue early; lands during compute

    const int kv0 = kt * 64;
    if (kv0 < kv_need_w) {
      const char* kb = (const char*)&kbuf[kt & 1][0];
      const char* vb = (const char*)&vbuf[kt & 1][0];

      // QK^T (swapped): sacc[t16] = S^T [16k x 16q], log2-domain scores
      f32x4 sacc[4] = {};
      __builtin_amdgcn_s_setprio(1);
      #pragma unroll
      for (int t16 = 0; t16 < 4; ++t16) {
        s16x8 kf0 = *(const s16x8*)(kb + t16 * 2048 + koff0);
        s16x8 kf1 = *(const s16x8*)(kb + t16 * 2048 + koff1);
        sacc[t16] = __builtin_amdgcn_mfma_f32_16x16x32_bf16(kf0, qfrag[0], sacc[t16], 0, 0, 0);
        sacc[t16] = __builtin_amdgcn_mfma_f32_16x16x32_bf16(kf1, qfrag[1], sacc[t16], 0, 0, 0);
      }
      __builtin_amdgcn_s_setprio(0);

      // fused mask + fixed-max exp2 + sum + cvt_pk (register-cheap, R10)
      u32x4 w0, w1;
      float lsum = 0.0f;
      if (kv0 + 64 <= kvmin_w) {              // wave-uniform full tile
        #pragma unroll
        for (int t16 = 0; t16 < 4; ++t16) {
          float a = exp2f_raw(sacc[t16][0]);
          float b = exp2f_raw(sacc[t16][1]);
          float c = exp2f_raw(sacc[t16][2]);
          float d = exp2f_raw(sacc[t16][3]);
          lsum += (a + b) + (c + d);
          u32 lo = cvtpk(a, b), hi = cvtpk(c, d);
          if (t16 < 2) { w0[2 * t16] = lo; w0[2 * t16 + 1] = hi; }
          else         { w1[2 * (t16 - 2)] = lo; w1[2 * (t16 - 2) + 1] = hi; }
        }
      } else {
        const int kbq = kv0 + lg * 4;
        #pragma unroll
        for (int t16 = 0; t16 < 4; ++t16) {
          float a = (kbq + t16 * 16     < my_kvlen) ? exp2f_raw(sacc[t16][0]) : 0.0f;
          float b = (kbq + t16 * 16 + 1 < my_kvlen) ? exp2f_raw(sacc[t16][1]) : 0.0f;
          float c = (kbq + t16 * 16 + 2 < my_kvlen) ? exp2f_raw(sacc[t16][2]) : 0.0f;
          float d = (kbq + t16 * 16 + 3 < my_kvlen) ? exp2f_raw(sacc[t16][3]) : 0.0f;
          lsum += (a + b) + (c + d);
          u32 lo = cvtpk(a, b), hi = cvtpk(c, d);
          if (t16 < 2) { w0[2 * t16] = lo; w0[2 * t16 + 1] = hi; }
          else         { w1[2 * (t16 - 2)] = lo; w1[2 * (t16 - 2) + 1] = hi; }
        }
      }
      l_run += lsum;
      s16x8 pf0 = __builtin_bit_cast(s16x8, w0);
      s16x8 pf1 = __builtin_bit_cast(s16x8, w1);

      // PV: gathered V fragments, straight b128 reads (pre-swizzled)
      __builtin_amdgcn_s_setprio(1);
      #pragma unroll
      for (int dt = 0; dt < 4; ++dt) {
        s16x8 vf0 = *(const s16x8*)(vb + dt * 2048 + voff0);
        s16x8 vf1 = *(const s16x8*)(vb + dt * 2048 + voff1);
        oacc[dt] = __builtin_amdgcn_mfma_f32_16x16x32_bf16(pf0, vf0, oacc[dt], 0, 0, 0);
        oacc[dt] = __builtin_amdgcn_mfma_f32_16x16x32_bf16(pf1, vf1, oacc[dt], 0, 0, 0);
      }
      __builtin_amdgcn_s_setprio(0);
    }

    __syncthreads();                          // reads of buf[kt&1] done (all waves)
    if (kt + 1 < nt) {
      writelds((kt + 1) & 1);                 // staged regs -> other buffer
      __syncthreads();                        // writes visible before next reads
    }
  }

  // epilogue: reduce l across the 4 replica lane-groups, normalize, store
  l_run += __shfl_xor(l_run, 16);
  l_run += __shfl_xor(l_run, 32);
  float linv = 1.0f / l_run;
  float li_q[4];
  #pragma unroll
  for (int r = 0; r < 4; ++r) li_q[r] = __shfl(linv, lg * 4 + r);
  #pragma unroll
  for (int r = 0; r < 4; ++r) {
    int qo = qw + lg * 4 + r;
    if (qo < L_TOK) {
      float* dst = Og + ((size_t)(bh * L_TOK + qo)) * DHEAD + l15;
      #pragma unroll
      for (int dt = 0; dt < 4; ++dt) dst[dt * 16] = oacc[dt][r] * li_q[r];
    }
  }
}

extern "C" void kernel_launch(void* const* d_in, const int* in_sizes, int n_in,
                              void* d_out, int out_size, void* d_ws, size_t ws_size,
                              hipStream_t stream) {
  const float* q = (const float*)d_in[0];
  const float* k = (const float*)d_in[1];
  const float* v = (const float*)d_in[2];
  float* o = (float*)d_out;
  (void)d_ws; (void)ws_size;
  var_attn13<<<768, 512, 0, stream>>>(q, k, v, o);
}

// Round 15
// 33.164 us; speedup vs baseline: 1.9506x; 1.1509x over previous
//
#include <hip/hip_runtime.h>

// VAR flex-attention, MI355X gfx950. Mask == "q attends to keys [0, block_end(q))".
// R14: R13 single-kernel (in-kernel f32->bf16 staging into swizzled K /
// gathered-V^T LDS, fused fixed-max exp2 softmax, long-first XCD dispatch)
// with: (1) __launch_bounds__(512,4) -> VGPR cap 128, kills the ~15MB/launch
// scratch spill R13 showed (WRITE_SIZE 37.4MB vs O's 21.8MB); (2) triple-
// buffered LDS (3x16KB) -> ONE barrier per iter (write buf[(kt+1)%3] after
// compute; that buffer was last read at iter kt-2, already fenced).

typedef float  f32x4 __attribute__((ext_vector_type(4)));
typedef short  s16x8 __attribute__((ext_vector_type(8)));
typedef unsigned int u32;
typedef u32    u32x4 __attribute__((ext_vector_type(4)));

#define L_TOK 680
#define DHEAD 64
#define NBH   128
#define SCALE_LOG2 0.18033688011112042f   // (1/8) * log2(e)

__device__ __forceinline__ int kv_len(int q) {
  return q < 1 ? 1 : q < 5 ? 5 : q < 14 ? 14 : q < 30 ? 30 : q < 55 ? 55
       : q < 91 ? 91 : q < 155 ? 155 : q < 255 ? 255 : q < 424 ? 424 : L_TOK;
}

__device__ __forceinline__ short f2bf(float x) {
  unsigned u = __float_as_uint(x);
  return (short)((u + 0x7FFFu + ((u >> 16) & 1u)) >> 16);
}

__device__ __forceinline__ s16x8 cvt8(f32x4 a, f32x4 b, float sc) {
  s16x8 f;
  f[0] = f2bf(a[0] * sc); f[1] = f2bf(a[1] * sc);
  f[2] = f2bf(a[2] * sc); f[3] = f2bf(a[3] * sc);
  f[4] = f2bf(b[0] * sc); f[5] = f2bf(b[1] * sc);
  f[6] = f2bf(b[2] * sc); f[7] = f2bf(b[3] * sc);
  return f;
}

__device__ __forceinline__ float exp2f_raw(float x) {
  float r; asm("v_exp_f32 %0, %1" : "=v"(r) : "v"(x)); return r;
}
__device__ __forceinline__ u32 cvtpk(float lo, float hi) {
  u32 r; asm("v_cvt_pk_bf16_f32 %0, %1, %2" : "=v"(r) : "v"(lo), "v"(hi)); return r;
}

// ---- main (and only) kernel: 8 waves x 16q = 128q/block, 64-kv tiles -------
__global__ __launch_bounds__(512, 4) void var_attn14(
    const float* __restrict__ Qg, const float* __restrict__ Kg,
    const float* __restrict__ Vg, float* __restrict__ Og)
{
  const int tid  = threadIdx.x;
  const int lane = tid & 63, wave = tid >> 6;
  const int l15  = lane & 15, lg = lane >> 4;

  // dispatch: bid&7 -> XCD-stable bh-low (L2 reuse); long q-tiles first
  int bid  = blockIdx.x;                      // 0..767
  int bhlo = bid & 7;
  int t_   = bid >> 3;                        // 0..95
  int qbi  = t_ >> 4;                         // 0..5
  int bhhi = t_ & 15;
  int qb2  = (qbi < 3) ? (qbi + 3) : (5 - qbi);   // 3,4,5,2,1,0 (nt 11,11,11,7,4,3)
  int bh   = bhhi * 8 + bhlo;
  int qblk = qb2 * 128;

  __shared__ short kbuf[3][64 * DHEAD];       // 3 x 8KB, chunk16 ^ (r&7)
  __shared__ short vbuf[3][64 * DHEAD];       // 3 x 8KB, gathered V^T fragments

  const int qw        = qblk + wave * 16;
  const int qc        = min(qw + l15, L_TOK - 1);
  const int my_kvlen  = kv_len(qc);
  const int kvmin_w   = kv_len(min(qw, L_TOK - 1));
  const int kv_need_w = (qw < L_TOK) ? kv_len(min(qw + 15, L_TOK - 1)) : 0;
  const int nkv       = kv_len(min(qblk + 127, L_TOK - 1));
  const int nt        = (nkv + 63) >> 6;      // 3,4,7,11,11,11

  s16x8 qfrag[2];
  {
    const float* qp = Qg + ((size_t)(bh * L_TOK + qc)) * DHEAD + lg * 8;
    #pragma unroll
    for (int ks = 0; ks < 2; ++ks) {
      f32x4 a = *(const f32x4*)(qp + ks * 32);
      f32x4 b = *(const f32x4*)(qp + ks * 32 + 4);
      qfrag[ks] = cvt8(a, b, SCALE_LOG2);
    }
  }

  const float* kbase = Kg + (size_t)bh * L_TOK * DHEAD;
  const float* vbase = Vg + (size_t)bh * L_TOK * DHEAD;

  // ---- staging thread roles (per 64x64 tile) ----
  const int kr_s = tid >> 3, kc_s = tid & 7;              // K: row, 8-f32 chunk
  const int vd_s = tid & 63, lg_s = (tid >> 6) & 3, f_s = tid >> 8;  // V

  f32x4 kA, kB;        // staged K f32 (live across one compute phase)
  float vA[8];         // staged V f32

  auto loadregs = [&](int kt) {
    const int kv0 = kt * 64;
    const float* kp = kbase + (size_t)min(kv0 + kr_s, L_TOK - 1) * DHEAD + kc_s * 8;
    kA = *(const f32x4*)kp;
    kB = *(const f32x4*)(kp + 4);
    #pragma unroll
    for (int i = 0; i < 4; ++i) {
      int kv  = kv0 + f_s * 32 + lg_s * 4 + i;
      vA[i]     = vbase[(size_t)min(kv,      L_TOK - 1) * DHEAD + vd_s];
      vA[4 + i] = vbase[(size_t)min(kv + 16, L_TOK - 1) * DHEAD + vd_s];
    }
  };

  auto writelds = [&](int buf) {
    u32x4 kw;
    kw[0] = cvtpk(kA[0], kA[1]); kw[1] = cvtpk(kA[2], kA[3]);
    kw[2] = cvtpk(kB[0], kB[1]); kw[3] = cvtpk(kB[2], kB[3]);
    *(u32x4*)(&kbuf[buf][kr_s * 64 + ((kc_s ^ (kr_s & 7)) * 8)]) = kw;
    u32x4 vw;
    vw[0] = cvtpk(vA[0], vA[1]); vw[1] = cvtpk(vA[2], vA[3]);
    vw[2] = cvtpk(vA[4], vA[5]); vw[3] = cvtpk(vA[6], vA[7]);
    int pos = (2 * lg_s + f_s) ^ (vd_s & 7);
    *(u32x4*)(&vbuf[buf][vd_s * 64 + pos * 8]) = vw;
  };

  // hoisted loop-invariant LDS byte offsets (compute phase)
  const int swz   = l15 & 7;
  const int koff0 = l15 * 128 + ((lg    ) ^ swz) * 16;
  const int koff1 = l15 * 128 + ((lg + 4) ^ swz) * 16;
  const int voff0 = l15 * 128 + ((2 * lg    ) ^ swz) * 16;
  const int voff1 = l15 * 128 + ((2 * lg + 1) ^ swz) * 16;

  f32x4 oacc[4] = {};
  float l_run = 0.0f;

  // prologue: stage tile 0 into buf 0
  loadregs(0);
  writelds(0);
  __syncthreads();

  int bcur = 0;                               // kt % 3
  for (int kt = 0; kt < nt; ++kt) {
    if (kt + 1 < nt) loadregs(kt + 1);        // issue early; lands during compute

    const int kv0 = kt * 64;
    if (kv0 < kv_need_w) {
      const char* kb = (const char*)&kbuf[bcur][0];
      const char* vb = (const char*)&vbuf[bcur][0];

      // QK^T (swapped): sacc[t16] = S^T [16k x 16q], log2-domain scores
      f32x4 sacc[4] = {};
      __builtin_amdgcn_s_setprio(1);
      #pragma unroll
      for (int t16 = 0; t16 < 4; ++t16) {
        s16x8 kf0 = *(const s16x8*)(kb + t16 * 2048 + koff0);
        s16x8 kf1 = *(const s16x8*)(kb + t16 * 2048 + koff1);
        sacc[t16] = __builtin_amdgcn_mfma_f32_16x16x32_bf16(kf0, qfrag[0], sacc[t16], 0, 0, 0);
        sacc[t16] = __builtin_amdgcn_mfma_f32_16x16x32_bf16(kf1, qfrag[1], sacc[t16], 0, 0, 0);
      }
      __builtin_amdgcn_s_setprio(0);

      // fused mask + fixed-max exp2 + sum + cvt_pk (register-cheap)
      u32x4 w0, w1;
      float lsum = 0.0f;
      if (kv0 + 64 <= kvmin_w) {              // wave-uniform full tile
        #pragma unroll
        for (int t16 = 0; t16 < 4; ++t16) {
          float a = exp2f_raw(sacc[t16][0]);
          float b = exp2f_raw(sacc[t16][1]);
          float c = exp2f_raw(sacc[t16][2]);
          float d = exp2f_raw(sacc[t16][3]);
          lsum += (a + b) + (c + d);
          u32 lo = cvtpk(a, b), hi = cvtpk(c, d);
          if (t16 < 2) { w0[2 * t16] = lo; w0[2 * t16 + 1] = hi; }
          else         { w1[2 * (t16 - 2)] = lo; w1[2 * (t16 - 2) + 1] = hi; }
        }
      } else {
        const int kbq = kv0 + lg * 4;
        #pragma unroll
        for (int t16 = 0; t16 < 4; ++t16) {
          float a = (kbq + t16 * 16     < my_kvlen) ? exp2f_raw(sacc[t16][0]) : 0.0f;
          float b = (kbq + t16 * 16 + 1 < my_kvlen) ? exp2f_raw(sacc[t16][1]) : 0.0f;
          float c = (kbq + t16 * 16 + 2 < my_kvlen) ? exp2f_raw(sacc[t16][2]) : 0.0f;
          float d = (kbq + t16 * 16 + 3 < my_kvlen) ? exp2f_raw(sacc[t16][3]) : 0.0f;
          lsum += (a + b) + (c + d);
          u32 lo = cvtpk(a, b), hi = cvtpk(c, d);
          if (t16 < 2) { w0[2 * t16] = lo; w0[2 * t16 + 1] = hi; }
          else         { w1[2 * (t16 - 2)] = lo; w1[2 * (t16 - 2) + 1] = hi; }
        }
      }
      l_run += lsum;
      s16x8 pf0 = __builtin_bit_cast(s16x8, w0);
      s16x8 pf1 = __builtin_bit_cast(s16x8, w1);

      // PV: gathered V fragments, straight b128 reads (pre-swizzled)
      __builtin_amdgcn_s_setprio(1);
      #pragma unroll
      for (int dt = 0; dt < 4; ++dt) {
        s16x8 vf0 = *(const s16x8*)(vb + dt * 2048 + voff0);
        s16x8 vf1 = *(const s16x8*)(vb + dt * 2048 + voff1);
        oacc[dt] = __builtin_amdgcn_mfma_f32_16x16x32_bf16(pf0, vf0, oacc[dt], 0, 0, 0);
        oacc[dt] = __builtin_amdgcn_mfma_f32_16x16x32_bf16(pf1, vf1, oacc[dt], 0, 0, 0);
      }
      __builtin_amdgcn_s_setprio(0);
    }

    // stage tile kt+1 into buf (kt+1)%3: that buffer was last READ at iter
    // kt-2 and two barriers have passed since -> safe with ONE barrier here.
    if (kt + 1 < nt) {
      int bnext = (bcur == 2) ? 0 : bcur + 1;
      writelds(bnext);
      __syncthreads();
      bcur = bnext;
    }
  }

  // epilogue: reduce l across the 4 replica lane-groups, normalize, store
  l_run += __shfl_xor(l_run, 16);
  l_run += __shfl_xor(l_run, 32);
  float linv = 1.0f / l_run;
  float li_q[4];
  #pragma unroll
  for (int r = 0; r < 4; ++r) li_q[r] = __shfl(linv, lg * 4 + r);
  #pragma unroll
  for (int r = 0; r < 4; ++r) {
    int qo = qw + lg * 4 + r;
    if (qo < L_TOK) {
      float* dst = Og + ((size_t)(bh * L_TOK + qo)) * DHEAD + l15;
      #pragma unroll
      for (int dt = 0; dt < 4; ++dt) dst[dt * 16] = oacc[dt][r] * li_q[r];
    }
  }
}

extern "C" void kernel_launch(void* const* d_in, const int* in_sizes, int n_in,
                              void* d_out, int out_size, void* d_ws, size_t ws_size,
                              hipStream_t stream) {
  const float* q = (const float*)d_in[0];
  const float* k = (const float*)d_in[1];
  const float* v = (const float*)d_in[2];
  float* o = (float*)d_out;
  (void)d_ws; (void)ws_size;
  var_attn14<<<768, 512, 0, stream>>>(q, k, v, o);
}

// Round 16
// 32.220 us; speedup vs baseline: 2.0078x; 1.0293x over previous
//
#include <hip/hip_runtime.h>

// VAR flex-attention, MI355X gfx950. Mask == "q attends to keys [0, block_end(q))".
// R15: R14's proven single-kernel schedule (in-kernel f32->bf16 reg-staging
// into swizzled-K / gathered-V^T LDS, 3-buffer, ONE barrier/iter, fused
// fixed-max exp2 softmax, long-first XCD dispatch, no spill) with 32q/WAVE:
// 256-thread / 4-wave blocks, each wave owns two 16q halves; one K/V ds_read
// feeds both halves' MFMAs -> LDS-read traffic per q HALVES (R14's dominant
// pipe: ~17us/CU of ds_read_b128 time). launch_bounds(256,3): VGPR cap 170.

typedef float  f32x4 __attribute__((ext_vector_type(4)));
typedef short  s16x8 __attribute__((ext_vector_type(8)));
typedef unsigned int u32;
typedef u32    u32x4 __attribute__((ext_vector_type(4)));

#define L_TOK 680
#define DHEAD 64
#define NBH   128
#define SCALE_LOG2 0.18033688011112042f   // (1/8) * log2(e)

__device__ __forceinline__ int kv_len(int q) {
  return q < 1 ? 1 : q < 5 ? 5 : q < 14 ? 14 : q < 30 ? 30 : q < 55 ? 55
       : q < 91 ? 91 : q < 155 ? 155 : q < 255 ? 255 : q < 424 ? 424 : L_TOK;
}

__device__ __forceinline__ short f2bf(float x) {
  unsigned u = __float_as_uint(x);
  return (short)((u + 0x7FFFu + ((u >> 16) & 1u)) >> 16);
}

__device__ __forceinline__ s16x8 cvt8(f32x4 a, f32x4 b, float sc) {
  s16x8 f;
  f[0] = f2bf(a[0] * sc); f[1] = f2bf(a[1] * sc);
  f[2] = f2bf(a[2] * sc); f[3] = f2bf(a[3] * sc);
  f[4] = f2bf(b[0] * sc); f[5] = f2bf(b[1] * sc);
  f[6] = f2bf(b[2] * sc); f[7] = f2bf(b[3] * sc);
  return f;
}

__device__ __forceinline__ float exp2f_raw(float x) {
  float r; asm("v_exp_f32 %0, %1" : "=v"(r) : "v"(x)); return r;
}
__device__ __forceinline__ u32 cvtpk(float lo, float hi) {
  u32 r; asm("v_cvt_pk_bf16_f32 %0, %1, %2" : "=v"(r) : "v"(lo), "v"(hi)); return r;
}

// ---- main kernel: 4 waves x 32 q = 128q/block, 64-kv tiles, 3-buf 1-barrier -
__global__ __launch_bounds__(256, 3) void var_attn15(
    const float* __restrict__ Qg, const float* __restrict__ Kg,
    const float* __restrict__ Vg, float* __restrict__ Og)
{
  const int tid  = threadIdx.x;
  const int lane = tid & 63, wave = tid >> 6;
  const int l15  = lane & 15, lg = lane >> 4;

  // dispatch: bid&7 -> XCD-stable bh-low (L2 reuse); long q-tiles first
  int bid  = blockIdx.x;                      // 0..767
  int bhlo = bid & 7;
  int t_   = bid >> 3;                        // 0..95
  int qbi  = t_ >> 4;                         // 0..5
  int bhhi = t_ & 15;
  int qb2  = (qbi < 3) ? (qbi + 3) : (5 - qbi);   // 3,4,5,2,1,0 (nt 11,11,11,7,4,3)
  int bh   = bhhi * 8 + bhlo;
  int qblk = qb2 * 128;

  __shared__ short kbuf[3][64 * DHEAD];       // 3 x 8KB, chunk16 ^ (r&7)
  __shared__ short vbuf[3][64 * DHEAD];       // 3 x 8KB, gathered V^T fragments

  const int qw        = qblk + wave * 32;     // wave's 32-q span
  const int q0c       = min(qw + l15,      L_TOK - 1);
  const int q1c       = min(qw + 16 + l15, L_TOK - 1);
  const int kvlen0    = kv_len(q0c);
  const int kvlen1    = kv_len(q1c);
  const int kvmin_w   = kv_len(min(qw, L_TOK - 1));
  const int kv_need_w = (qw < L_TOK) ? kv_len(min(qw + 31, L_TOK - 1)) : 0;
  const int nkv       = kv_len(min(qblk + 127, L_TOK - 1));
  const int nt        = (nkv + 63) >> 6;      // 3,4,7,11,11,11

  // Q fragments for both q-halves, pre-scaled into log2 domain
  s16x8 qf0[2], qf1[2];
  {
    const float* qp0 = Qg + ((size_t)(bh * L_TOK + q0c)) * DHEAD + lg * 8;
    const float* qp1 = Qg + ((size_t)(bh * L_TOK + q1c)) * DHEAD + lg * 8;
    #pragma unroll
    for (int ks = 0; ks < 2; ++ks) {
      f32x4 a0 = *(const f32x4*)(qp0 + ks * 32);
      f32x4 b0 = *(const f32x4*)(qp0 + ks * 32 + 4);
      qf0[ks] = cvt8(a0, b0, SCALE_LOG2);
      f32x4 a1 = *(const f32x4*)(qp1 + ks * 32);
      f32x4 b1 = *(const f32x4*)(qp1 + ks * 32 + 4);
      qf1[ks] = cvt8(a1, b1, SCALE_LOG2);
    }
  }

  const float* kbase = Kg + (size_t)bh * L_TOK * DHEAD;
  const float* vbase = Vg + (size_t)bh * L_TOK * DHEAD;

  // ---- staging thread roles (256 threads per 64x64 tile) ----
  // K: thread -> row kr_s = tid>>2, 16-f32 chunk kc_s = tid&3
  const int kr_s = tid >> 2, kc_s = tid & 3;
  // V: thread -> d vd_s = tid&63, lane-group lg_s = tid>>6 (f = 0,1 both)
  const int vd_s = tid & 63, lg_s = tid >> 6;

  f32x4 kA, kB, kC, kD;   // staged K f32 (live across one compute phase)
  float vA[16];           // staged V f32

  auto loadregs = [&](int kt) {
    const int kv0 = kt * 64;
    const float* kp = kbase + (size_t)min(kv0 + kr_s, L_TOK - 1) * DHEAD + kc_s * 16;
    kA = *(const f32x4*)kp;
    kB = *(const f32x4*)(kp + 4);
    kC = *(const f32x4*)(kp + 8);
    kD = *(const f32x4*)(kp + 12);
    #pragma unroll
    for (int f = 0; f < 2; ++f)
      #pragma unroll
      for (int i = 0; i < 4; ++i) {
        int kv = kv0 + f * 32 + lg_s * 4 + i;
        vA[f * 8 + i]     = vbase[(size_t)min(kv,      L_TOK - 1) * DHEAD + vd_s];
        vA[f * 8 + 4 + i] = vbase[(size_t)min(kv + 16, L_TOK - 1) * DHEAD + vd_s];
      }
  };

  auto writelds = [&](int buf) {
    u32x4 k0, k1;
    k0[0] = cvtpk(kA[0], kA[1]); k0[1] = cvtpk(kA[2], kA[3]);
    k0[2] = cvtpk(kB[0], kB[1]); k0[3] = cvtpk(kB[2], kB[3]);
    k1[0] = cvtpk(kC[0], kC[1]); k1[1] = cvtpk(kC[2], kC[3]);
    k1[2] = cvtpk(kD[0], kD[1]); k1[3] = cvtpk(kD[2], kD[3]);
    *(u32x4*)(&kbuf[buf][kr_s * 64 + (((2 * kc_s    ) ^ (kr_s & 7)) * 8)]) = k0;
    *(u32x4*)(&kbuf[buf][kr_s * 64 + (((2 * kc_s + 1) ^ (kr_s & 7)) * 8)]) = k1;
    u32x4 v0, v1;
    v0[0] = cvtpk(vA[0],  vA[1]);  v0[1] = cvtpk(vA[2],  vA[3]);
    v0[2] = cvtpk(vA[4],  vA[5]);  v0[3] = cvtpk(vA[6],  vA[7]);
    v1[0] = cvtpk(vA[8],  vA[9]);  v1[1] = cvtpk(vA[10], vA[11]);
    v1[2] = cvtpk(vA[12], vA[13]); v1[3] = cvtpk(vA[14], vA[15]);
    *(u32x4*)(&vbuf[buf][vd_s * 64 + (((2 * lg_s    ) ^ (vd_s & 7)) * 8)]) = v0;
    *(u32x4*)(&vbuf[buf][vd_s * 64 + (((2 * lg_s + 1) ^ (vd_s & 7)) * 8)]) = v1;
  };

  // hoisted loop-invariant LDS byte offsets (compute phase)
  const int swz   = l15 & 7;
  const int koff0 = l15 * 128 + ((lg    ) ^ swz) * 16;
  const int koff1 = l15 * 128 + ((lg + 4) ^ swz) * 16;
  const int voff0 = l15 * 128 + ((2 * lg    ) ^ swz) * 16;
  const int voff1 = l15 * 128 + ((2 * lg + 1) ^ swz) * 16;

  f32x4 o0[4] = {}, o1[4] = {};
  float l0 = 0.0f, l1 = 0.0f;

  // prologue: stage tile 0 into buf 0
  loadregs(0);
  writelds(0);
  __syncthreads();

  int bcur = 0;                               // kt % 3
  for (int kt = 0; kt < nt; ++kt) {
    if (kt + 1 < nt) loadregs(kt + 1);        // issue early; lands during compute

    const int kv0 = kt * 64;
    if (kv0 < kv_need_w) {
      const char* kb = (const char*)&kbuf[bcur][0];
      const char* vb = (const char*)&vbuf[bcur][0];

      // QK^T (swapped): one K read feeds both q-halves
      f32x4 s0a[4], s1a[4];
      #pragma unroll
      for (int t16 = 0; t16 < 4; ++t16) { s0a[t16] = (f32x4)0; s1a[t16] = (f32x4)0; }
      __builtin_amdgcn_s_setprio(1);
      #pragma unroll
      for (int t16 = 0; t16 < 4; ++t16) {
        s16x8 kfa = *(const s16x8*)(kb + t16 * 2048 + koff0);
        s16x8 kfb = *(const s16x8*)(kb + t16 * 2048 + koff1);
        s0a[t16] = __builtin_amdgcn_mfma_f32_16x16x32_bf16(kfa, qf0[0], s0a[t16], 0, 0, 0);
        s0a[t16] = __builtin_amdgcn_mfma_f32_16x16x32_bf16(kfb, qf0[1], s0a[t16], 0, 0, 0);
        s1a[t16] = __builtin_amdgcn_mfma_f32_16x16x32_bf16(kfa, qf1[0], s1a[t16], 0, 0, 0);
        s1a[t16] = __builtin_amdgcn_mfma_f32_16x16x32_bf16(kfb, qf1[1], s1a[t16], 0, 0, 0);
      }
      __builtin_amdgcn_s_setprio(0);

      // fused mask + fixed-max exp2 + sum + cvt_pk, both halves (no staging
      // arrays: each sacc quad -> 4 exp2 -> 2 packed u32, then dead)
      u32x4 w00, w01, w10, w11;
      float ls0 = 0.0f, ls1 = 0.0f;
      if (kv0 + 64 <= kvmin_w) {              // wave-uniform full tile
        #pragma unroll
        for (int t16 = 0; t16 < 4; ++t16) {
          float a = exp2f_raw(s0a[t16][0]);
          float b = exp2f_raw(s0a[t16][1]);
          float c = exp2f_raw(s0a[t16][2]);
          float d = exp2f_raw(s0a[t16][3]);
          ls0 += (a + b) + (c + d);
          u32 lo0 = cvtpk(a, b), hi0 = cvtpk(c, d);
          float e = exp2f_raw(s1a[t16][0]);
          float f = exp2f_raw(s1a[t16][1]);
          float g = exp2f_raw(s1a[t16][2]);
          float h = exp2f_raw(s1a[t16][3]);
          ls1 += (e + f) + (g + h);
          u32 lo1 = cvtpk(e, f), hi1 = cvtpk(g, h);
          if (t16 < 2) {
            w00[2 * t16] = lo0; w00[2 * t16 + 1] = hi0;
            w10[2 * t16] = lo1; w10[2 * t16 + 1] = hi1;
          } else {
            w01[2 * (t16 - 2)] = lo0; w01[2 * (t16 - 2) + 1] = hi0;
            w11[2 * (t16 - 2)] = lo1; w11[2 * (t16 - 2) + 1] = hi1;
          }
        }
      } else {
        const int kbq = kv0 + lg * 4;
        #pragma unroll
        for (int t16 = 0; t16 < 4; ++t16) {
          const int k0i = kbq + t16 * 16;
          float a = (k0i     < kvlen0) ? exp2f_raw(s0a[t16][0]) : 0.0f;
          float b = (k0i + 1 < kvlen0) ? exp2f_raw(s0a[t16][1]) : 0.0f;
          float c = (k0i + 2 < kvlen0) ? exp2f_raw(s0a[t16][2]) : 0.0f;
          float d = (k0i + 3 < kvlen0) ? exp2f_raw(s0a[t16][3]) : 0.0f;
          ls0 += (a + b) + (c + d);
          u32 lo0 = cvtpk(a, b), hi0 = cvtpk(c, d);
          float e = (k0i     < kvlen1) ? exp2f_raw(s1a[t16][0]) : 0.0f;
          float f = (k0i + 1 < kvlen1) ? exp2f_raw(s1a[t16][1]) : 0.0f;
          float g = (k0i + 2 < kvlen1) ? exp2f_raw(s1a[t16][2]) : 0.0f;
          float h = (k0i + 3 < kvlen1) ? exp2f_raw(s1a[t16][3]) : 0.0f;
          ls1 += (e + f) + (g + h);
          u32 lo1 = cvtpk(e, f), hi1 = cvtpk(g, h);
          if (t16 < 2) {
            w00[2 * t16] = lo0; w00[2 * t16 + 1] = hi0;
            w10[2 * t16] = lo1; w10[2 * t16 + 1] = hi1;
          } else {
            w01[2 * (t16 - 2)] = lo0; w01[2 * (t16 - 2) + 1] = hi0;
            w11[2 * (t16 - 2)] = lo1; w11[2 * (t16 - 2) + 1] = hi1;
          }
        }
      }
      l0 += ls0;
      l1 += ls1;
      s16x8 pf00 = __builtin_bit_cast(s16x8, w00);
      s16x8 pf01 = __builtin_bit_cast(s16x8, w01);
      s16x8 pf10 = __builtin_bit_cast(s16x8, w10);
      s16x8 pf11 = __builtin_bit_cast(s16x8, w11);

      // PV: one V read feeds both q-halves
      __builtin_amdgcn_s_setprio(1);
      #pragma unroll
      for (int dt = 0; dt < 4; ++dt) {
        s16x8 vf0 = *(const s16x8*)(vb + dt * 2048 + voff0);
        s16x8 vf1 = *(const s16x8*)(vb + dt * 2048 + voff1);
        o0[dt] = __builtin_amdgcn_mfma_f32_16x16x32_bf16(pf00, vf0, o0[dt], 0, 0, 0);
        o0[dt] = __builtin_amdgcn_mfma_f32_16x16x32_bf16(pf01, vf1, o0[dt], 0, 0, 0);
        o1[dt] = __builtin_amdgcn_mfma_f32_16x16x32_bf16(pf10, vf0, o1[dt], 0, 0, 0);
        o1[dt] = __builtin_amdgcn_mfma_f32_16x16x32_bf16(pf11, vf1, o1[dt], 0, 0, 0);
      }
      __builtin_amdgcn_s_setprio(0);
    }

    // stage tile kt+1 into buf (bcur+1)%3: last READ at iter kt-2, two
    // barriers ago -> safe with ONE barrier here.
    if (kt + 1 < nt) {
      int bnext = (bcur == 2) ? 0 : bcur + 1;
      writelds(bnext);
      __syncthreads();
      bcur = bnext;
    }
  }

  // epilogue: reduce l across the 4 replica lane-groups, normalize, store
  l0 += __shfl_xor(l0, 16); l0 += __shfl_xor(l0, 32);
  l1 += __shfl_xor(l1, 16); l1 += __shfl_xor(l1, 32);
  float li0 = 1.0f / l0, li1 = 1.0f / l1;
  float s0q[4], s1q[4];
  #pragma unroll
  for (int r = 0; r < 4; ++r) {
    s0q[r] = __shfl(li0, lg * 4 + r);
    s1q[r] = __shfl(li1, lg * 4 + r);
  }
  #pragma unroll
  for (int r = 0; r < 4; ++r) {
    int qo0 = qw + lg * 4 + r;
    if (qo0 < L_TOK) {
      float* dst = Og + ((size_t)(bh * L_TOK + qo0)) * DHEAD + l15;
      #pragma unroll
      for (int dt = 0; dt < 4; ++dt) dst[dt * 16] = o0[dt][r] * s0q[r];
    }
    int qo1 = qw + 16 + lg * 4 + r;
    if (qo1 < L_TOK) {
      float* dst = Og + ((size_t)(bh * L_TOK + qo1)) * DHEAD + l15;
      #pragma unroll
      for (int dt = 0; dt < 4; ++dt) dst[dt * 16] = o1[dt][r] * s1q[r];
    }
  }
}

extern "C" void kernel_launch(void* const* d_in, const int* in_sizes, int n_in,
                              void* d_out, int out_size, void* d_ws, size_t ws_size,
                              hipStream_t stream) {
  const float* q = (const float*)d_in[0];
  const float* k = (const float*)d_in[1];
  const float* v = (const float*)d_in[2];
  float* o = (float*)d_out;
  (void)d_ws; (void)ws_size;
  var_attn15<<<768, 256, 0, stream>>>(q, k, v, o);
}

// Round 17
// 30.446 us; speedup vs baseline: 2.1247x; 1.0582x over previous
//
#include <hip/hip_runtime.h>

// VAR flex-attention, MI355X gfx950. Mask == "q attends to keys [0, block_end(q))".
// R16: R15 (single-kernel, 4 waves x 32q, in-kernel f32->bf16 reg-staging into
// swizzled-K / gathered-V^T LDS, 3-buffer, ONE barrier/iter, fused fixed-max
// exp2 softmax, XCD-keyed dispatch) with ONE change: balanced qbi->qb2 map.
// True nt per q-strip = {3,7,7,11,11,11} (q=255 -> kvlen 424 -> nt 7, not 4!).
// Round-robin CU placement gives each CU qbi groups {0,2,4} or {1,3,5};
// old map (3,4,5,2,1,0): sums {11,11,7}=29 vs {11,7,3}=21 (16% tail).
// new map (3,5,4,2,0,1): sums {11,11,3}=25 vs {11,7,7}=25 (exact balance).

typedef float  f32x4 __attribute__((ext_vector_type(4)));
typedef short  s16x8 __attribute__((ext_vector_type(8)));
typedef unsigned int u32;
typedef u32    u32x4 __attribute__((ext_vector_type(4)));

#define L_TOK 680
#define DHEAD 64
#define NBH   128
#define SCALE_LOG2 0.18033688011112042f   // (1/8) * log2(e)

__device__ __forceinline__ int kv_len(int q) {
  return q < 1 ? 1 : q < 5 ? 5 : q < 14 ? 14 : q < 30 ? 30 : q < 55 ? 55
       : q < 91 ? 91 : q < 155 ? 155 : q < 255 ? 255 : q < 424 ? 424 : L_TOK;
}

__device__ __forceinline__ short f2bf(float x) {
  unsigned u = __float_as_uint(x);
  return (short)((u + 0x7FFFu + ((u >> 16) & 1u)) >> 16);
}

__device__ __forceinline__ s16x8 cvt8(f32x4 a, f32x4 b, float sc) {
  s16x8 f;
  f[0] = f2bf(a[0] * sc); f[1] = f2bf(a[1] * sc);
  f[2] = f2bf(a[2] * sc); f[3] = f2bf(a[3] * sc);
  f[4] = f2bf(b[0] * sc); f[5] = f2bf(b[1] * sc);
  f[6] = f2bf(b[2] * sc); f[7] = f2bf(b[3] * sc);
  return f;
}

__device__ __forceinline__ float exp2f_raw(float x) {
  float r; asm("v_exp_f32 %0, %1" : "=v"(r) : "v"(x)); return r;
}
__device__ __forceinline__ u32 cvtpk(float lo, float hi) {
  u32 r; asm("v_cvt_pk_bf16_f32 %0, %1, %2" : "=v"(r) : "v"(lo), "v"(hi)); return r;
}

// ---- main kernel: 4 waves x 32 q = 128q/block, 64-kv tiles, 3-buf 1-barrier -
__global__ __launch_bounds__(256, 3) void var_attn16(
    const float* __restrict__ Qg, const float* __restrict__ Kg,
    const float* __restrict__ Vg, float* __restrict__ Og)
{
  const int tid  = threadIdx.x;
  const int lane = tid & 63, wave = tid >> 6;
  const int l15  = lane & 15, lg = lane >> 4;

  // dispatch: bid&7 -> XCD-stable bh-low (L2 reuse); balanced qbi->qb2 map
  int bid  = blockIdx.x;                      // 0..767
  int bhlo = bid & 7;
  int t_   = bid >> 3;                        // 0..95
  int qbi  = t_ >> 4;                         // 0..5
  int bhhi = t_ & 15;
  int qb2  = (qbi == 0) ? 3 : (qbi == 1) ? 5 : (qbi == 2) ? 4
           : (qbi == 3) ? 2 : (qbi == 4) ? 0 : 1;   // nts 11,11,11,7,3,7
  int bh   = bhhi * 8 + bhlo;
  int qblk = qb2 * 128;

  __shared__ short kbuf[3][64 * DHEAD];       // 3 x 8KB, chunk16 ^ (r&7)
  __shared__ short vbuf[3][64 * DHEAD];       // 3 x 8KB, gathered V^T fragments

  const int qw        = qblk + wave * 32;     // wave's 32-q span
  const int q0c       = min(qw + l15,      L_TOK - 1);
  const int q1c       = min(qw + 16 + l15, L_TOK - 1);
  const int kvlen0    = kv_len(q0c);
  const int kvlen1    = kv_len(q1c);
  const int kvmin_w   = kv_len(min(qw, L_TOK - 1));
  const int kv_need_w = (qw < L_TOK) ? kv_len(min(qw + 31, L_TOK - 1)) : 0;
  const int nkv       = kv_len(min(qblk + 127, L_TOK - 1));
  const int nt        = (nkv + 63) >> 6;      // 3,7,7,11,11,11

  // Q fragments for both q-halves, pre-scaled into log2 domain
  s16x8 qf0[2], qf1[2];
  {
    const float* qp0 = Qg + ((size_t)(bh * L_TOK + q0c)) * DHEAD + lg * 8;
    const float* qp1 = Qg + ((size_t)(bh * L_TOK + q1c)) * DHEAD + lg * 8;
    #pragma unroll
    for (int ks = 0; ks < 2; ++ks) {
      f32x4 a0 = *(const f32x4*)(qp0 + ks * 32);
      f32x4 b0 = *(const f32x4*)(qp0 + ks * 32 + 4);
      qf0[ks] = cvt8(a0, b0, SCALE_LOG2);
      f32x4 a1 = *(const f32x4*)(qp1 + ks * 32);
      f32x4 b1 = *(const f32x4*)(qp1 + ks * 32 + 4);
      qf1[ks] = cvt8(a1, b1, SCALE_LOG2);
    }
  }

  const float* kbase = Kg + (size_t)bh * L_TOK * DHEAD;
  const float* vbase = Vg + (size_t)bh * L_TOK * DHEAD;

  // ---- staging thread roles (256 threads per 64x64 tile) ----
  const int kr_s = tid >> 2, kc_s = tid & 3;  // K: row, 16-f32 chunk
  const int vd_s = tid & 63, lg_s = tid >> 6; // V: d, lane-group

  f32x4 kA, kB, kC, kD;   // staged K f32 (live across one compute phase)
  float vA[16];           // staged V f32

  auto loadregs = [&](int kt) {
    const int kv0 = kt * 64;
    const float* kp = kbase + (size_t)min(kv0 + kr_s, L_TOK - 1) * DHEAD + kc_s * 16;
    kA = *(const f32x4*)kp;
    kB = *(const f32x4*)(kp + 4);
    kC = *(const f32x4*)(kp + 8);
    kD = *(const f32x4*)(kp + 12);
    #pragma unroll
    for (int f = 0; f < 2; ++f)
      #pragma unroll
      for (int i = 0; i < 4; ++i) {
        int kv = kv0 + f * 32 + lg_s * 4 + i;
        vA[f * 8 + i]     = vbase[(size_t)min(kv,      L_TOK - 1) * DHEAD + vd_s];
        vA[f * 8 + 4 + i] = vbase[(size_t)min(kv + 16, L_TOK - 1) * DHEAD + vd_s];
      }
  };

  auto writelds = [&](int buf) {
    u32x4 k0, k1;
    k0[0] = cvtpk(kA[0], kA[1]); k0[1] = cvtpk(kA[2], kA[3]);
    k0[2] = cvtpk(kB[0], kB[1]); k0[3] = cvtpk(kB[2], kB[3]);
    k1[0] = cvtpk(kC[0], kC[1]); k1[1] = cvtpk(kC[2], kC[3]);
    k1[2] = cvtpk(kD[0], kD[1]); k1[3] = cvtpk(kD[2], kD[3]);
    *(u32x4*)(&kbuf[buf][kr_s * 64 + (((2 * kc_s    ) ^ (kr_s & 7)) * 8)]) = k0;
    *(u32x4*)(&kbuf[buf][kr_s * 64 + (((2 * kc_s + 1) ^ (kr_s & 7)) * 8)]) = k1;
    u32x4 v0, v1;
    v0[0] = cvtpk(vA[0],  vA[1]);  v0[1] = cvtpk(vA[2],  vA[3]);
    v0[2] = cvtpk(vA[4],  vA[5]);  v0[3] = cvtpk(vA[6],  vA[7]);
    v1[0] = cvtpk(vA[8],  vA[9]);  v1[1] = cvtpk(vA[10], vA[11]);
    v1[2] = cvtpk(vA[12], vA[13]); v1[3] = cvtpk(vA[14], vA[15]);
    *(u32x4*)(&vbuf[buf][vd_s * 64 + (((2 * lg_s    ) ^ (vd_s & 7)) * 8)]) = v0;
    *(u32x4*)(&vbuf[buf][vd_s * 64 + (((2 * lg_s + 1) ^ (vd_s & 7)) * 8)]) = v1;
  };

  // hoisted loop-invariant LDS byte offsets (compute phase)
  const int swz   = l15 & 7;
  const int koff0 = l15 * 128 + ((lg    ) ^ swz) * 16;
  const int koff1 = l15 * 128 + ((lg + 4) ^ swz) * 16;
  const int voff0 = l15 * 128 + ((2 * lg    ) ^ swz) * 16;
  const int voff1 = l15 * 128 + ((2 * lg + 1) ^ swz) * 16;

  f32x4 o0[4] = {}, o1[4] = {};
  float l0 = 0.0f, l1 = 0.0f;

  // prologue: stage tile 0 into buf 0
  loadregs(0);
  writelds(0);
  __syncthreads();

  int bcur = 0;                               // kt % 3
  for (int kt = 0; kt < nt; ++kt) {
    if (kt + 1 < nt) loadregs(kt + 1);        // issue early; lands during compute

    const int kv0 = kt * 64;
    if (kv0 < kv_need_w) {
      const char* kb = (const char*)&kbuf[bcur][0];
      const char* vb = (const char*)&vbuf[bcur][0];

      // QK^T (swapped): one K read feeds both q-halves
      f32x4 s0a[4], s1a[4];
      #pragma unroll
      for (int t16 = 0; t16 < 4; ++t16) { s0a[t16] = (f32x4)0; s1a[t16] = (f32x4)0; }
      __builtin_amdgcn_s_setprio(1);
      #pragma unroll
      for (int t16 = 0; t16 < 4; ++t16) {
        s16x8 kfa = *(const s16x8*)(kb + t16 * 2048 + koff0);
        s16x8 kfb = *(const s16x8*)(kb + t16 * 2048 + koff1);
        s0a[t16] = __builtin_amdgcn_mfma_f32_16x16x32_bf16(kfa, qf0[0], s0a[t16], 0, 0, 0);
        s0a[t16] = __builtin_amdgcn_mfma_f32_16x16x32_bf16(kfb, qf0[1], s0a[t16], 0, 0, 0);
        s1a[t16] = __builtin_amdgcn_mfma_f32_16x16x32_bf16(kfa, qf1[0], s1a[t16], 0, 0, 0);
        s1a[t16] = __builtin_amdgcn_mfma_f32_16x16x32_bf16(kfb, qf1[1], s1a[t16], 0, 0, 0);
      }
      __builtin_amdgcn_s_setprio(0);

      // fused mask + fixed-max exp2 + sum + cvt_pk, both halves
      u32x4 w00, w01, w10, w11;
      float ls0 = 0.0f, ls1 = 0.0f;
      if (kv0 + 64 <= kvmin_w) {              // wave-uniform full tile
        #pragma unroll
        for (int t16 = 0; t16 < 4; ++t16) {
          float a = exp2f_raw(s0a[t16][0]);
          float b = exp2f_raw(s0a[t16][1]);
          float c = exp2f_raw(s0a[t16][2]);
          float d = exp2f_raw(s0a[t16][3]);
          ls0 += (a + b) + (c + d);
          u32 lo0 = cvtpk(a, b), hi0 = cvtpk(c, d);
          float e = exp2f_raw(s1a[t16][0]);
          float f = exp2f_raw(s1a[t16][1]);
          float g = exp2f_raw(s1a[t16][2]);
          float h = exp2f_raw(s1a[t16][3]);
          ls1 += (e + f) + (g + h);
          u32 lo1 = cvtpk(e, f), hi1 = cvtpk(g, h);
          if (t16 < 2) {
            w00[2 * t16] = lo0; w00[2 * t16 + 1] = hi0;
            w10[2 * t16] = lo1; w10[2 * t16 + 1] = hi1;
          } else {
            w01[2 * (t16 - 2)] = lo0; w01[2 * (t16 - 2) + 1] = hi0;
            w11[2 * (t16 - 2)] = lo1; w11[2 * (t16 - 2) + 1] = hi1;
          }
        }
      } else {
        const int kbq = kv0 + lg * 4;
        #pragma unroll
        for (int t16 = 0; t16 < 4; ++t16) {
          const int k0i = kbq + t16 * 16;
          float a = (k0i     < kvlen0) ? exp2f_raw(s0a[t16][0]) : 0.0f;
          float b = (k0i + 1 < kvlen0) ? exp2f_raw(s0a[t16][1]) : 0.0f;
          float c = (k0i + 2 < kvlen0) ? exp2f_raw(s0a[t16][2]) : 0.0f;
          float d = (k0i + 3 < kvlen0) ? exp2f_raw(s0a[t16][3]) : 0.0f;
          ls0 += (a + b) + (c + d);
          u32 lo0 = cvtpk(a, b), hi0 = cvtpk(c, d);
          float e = (k0i     < kvlen1) ? exp2f_raw(s1a[t16][0]) : 0.0f;
          float f = (k0i + 1 < kvlen1) ? exp2f_raw(s1a[t16][1]) : 0.0f;
          float g = (k0i + 2 < kvlen1) ? exp2f_raw(s1a[t16][2]) : 0.0f;
          float h = (k0i + 3 < kvlen1) ? exp2f_raw(s1a[t16][3]) : 0.0f;
          ls1 += (e + f) + (g + h);
          u32 lo1 = cvtpk(e, f), hi1 = cvtpk(g, h);
          if (t16 < 2) {
            w00[2 * t16] = lo0; w00[2 * t16 + 1] = hi0;
            w10[2 * t16] = lo1; w10[2 * t16 + 1] = hi1;
          } else {
            w01[2 * (t16 - 2)] = lo0; w01[2 * (t16 - 2) + 1] = hi0;
            w11[2 * (t16 - 2)] = lo1; w11[2 * (t16 - 2) + 1] = hi1;
          }
        }
      }
      l0 += ls0;
      l1 += ls1;
      s16x8 pf00 = __builtin_bit_cast(s16x8, w00);
      s16x8 pf01 = __builtin_bit_cast(s16x8, w01);
      s16x8 pf10 = __builtin_bit_cast(s16x8, w10);
      s16x8 pf11 = __builtin_bit_cast(s16x8, w11);

      // PV: one V read feeds both q-halves
      __builtin_amdgcn_s_setprio(1);
      #pragma unroll
      for (int dt = 0; dt < 4; ++dt) {
        s16x8 vf0 = *(const s16x8*)(vb + dt * 2048 + voff0);
        s16x8 vf1 = *(const s16x8*)(vb + dt * 2048 + voff1);
        o0[dt] = __builtin_amdgcn_mfma_f32_16x16x32_bf16(pf00, vf0, o0[dt], 0, 0, 0);
        o0[dt] = __builtin_amdgcn_mfma_f32_16x16x32_bf16(pf01, vf1, o0[dt], 0, 0, 0);
        o1[dt] = __builtin_amdgcn_mfma_f32_16x16x32_bf16(pf10, vf0, o1[dt], 0, 0, 0);
        o1[dt] = __builtin_amdgcn_mfma_f32_16x16x32_bf16(pf11, vf1, o1[dt], 0, 0, 0);
      }
      __builtin_amdgcn_s_setprio(0);
    }

    // stage tile kt+1 into buf (bcur+1)%3: last READ at iter kt-2, two
    // barriers ago -> safe with ONE barrier here.
    if (kt + 1 < nt) {
      int bnext = (bcur == 2) ? 0 : bcur + 1;
      writelds(bnext);
      __syncthreads();
      bcur = bnext;
    }
  }

  // epilogue: reduce l across the 4 replica lane-groups, normalize, store
  l0 += __shfl_xor(l0, 16); l0 += __shfl_xor(l0, 32);
  l1 += __shfl_xor(l1, 16); l1 += __shfl_xor(l1, 32);
  float li0 = 1.0f / l0, li1 = 1.0f / l1;
  float s0q[4], s1q[4];
  #pragma unroll
  for (int r = 0; r < 4; ++r) {
    s0q[r] = __shfl(li0, lg * 4 + r);
    s1q[r] = __shfl(li1, lg * 4 + r);
  }
  #pragma unroll
  for (int r = 0; r < 4; ++r) {
    int qo0 = qw + lg * 4 + r;
    if (qo0 < L_TOK) {
      float* dst = Og + ((size_t)(bh * L_TOK + qo0)) * DHEAD + l15;
      #pragma unroll
      for (int dt = 0; dt < 4; ++dt) dst[dt * 16] = o0[dt][r] * s0q[r];
    }
    int qo1 = qw + 16 + lg * 4 + r;
    if (qo1 < L_TOK) {
      float* dst = Og + ((size_t)(bh * L_TOK + qo1)) * DHEAD + l15;
      #pragma unroll
      for (int dt = 0; dt < 4; ++dt) dst[dt * 16] = o1[dt][r] * s1q[r];
    }
  }
}

extern "C" void kernel_launch(void* const* d_in, const int* in_sizes, int n_in,
                              void* d_out, int out_size, void* d_ws, size_t ws_size,
                              hipStream_t stream) {
  const float* q = (const float*)d_in[0];
  const float* k = (const float*)d_in[1];
  const float* v = (const float*)d_in[2];
  float* o = (float*)d_out;
  (void)d_ws; (void)ws_size;
  var_attn16<<<768, 256, 0, stream>>>(q, k, v, o);
}

// Round 18
// 30.099 us; speedup vs baseline: 2.1493x; 1.0115x over previous
//
#include <hip/hip_runtime.h>

// VAR flex-attention, MI355X gfx950. Mask == "q attends to keys [0, block_end(q))".
// R17: R16 (single-kernel, 4 waves x 32q, reg-staged f32->bf16 into swizzled-K /
// gathered-V^T LDS, 3-buffer ONE barrier/iter, fused fixed-max exp2 softmax,
// balanced XCD dispatch) with the staging pipeline rotated across the barrier
// (T14 issue-early/write-late): loadregs(kt+2) is issued BEFORE the barrier at
// the end of iter kt, so the vmcnt wait at writelds(kt+2) [iter kt+1's end]
// has barrier-wait + one full compute phase of slack (~1100+ cyc > 900 HBM).
// Single staging reg set (loads reuse regs right after writelds consumes them).

typedef float  f32x4 __attribute__((ext_vector_type(4)));
typedef short  s16x8 __attribute__((ext_vector_type(8)));
typedef unsigned int u32;
typedef u32    u32x4 __attribute__((ext_vector_type(4)));

#define L_TOK 680
#define DHEAD 64
#define NBH   128
#define SCALE_LOG2 0.18033688011112042f   // (1/8) * log2(e)

__device__ __forceinline__ int kv_len(int q) {
  return q < 1 ? 1 : q < 5 ? 5 : q < 14 ? 14 : q < 30 ? 30 : q < 55 ? 55
       : q < 91 ? 91 : q < 155 ? 155 : q < 255 ? 255 : q < 424 ? 424 : L_TOK;
}

__device__ __forceinline__ short f2bf(float x) {
  unsigned u = __float_as_uint(x);
  return (short)((u + 0x7FFFu + ((u >> 16) & 1u)) >> 16);
}

__device__ __forceinline__ s16x8 cvt8(f32x4 a, f32x4 b, float sc) {
  s16x8 f;
  f[0] = f2bf(a[0] * sc); f[1] = f2bf(a[1] * sc);
  f[2] = f2bf(a[2] * sc); f[3] = f2bf(a[3] * sc);
  f[4] = f2bf(b[0] * sc); f[5] = f2bf(b[1] * sc);
  f[6] = f2bf(b[2] * sc); f[7] = f2bf(b[3] * sc);
  return f;
}

__device__ __forceinline__ float exp2f_raw(float x) {
  float r; asm("v_exp_f32 %0, %1" : "=v"(r) : "v"(x)); return r;
}
__device__ __forceinline__ u32 cvtpk(float lo, float hi) {
  u32 r; asm("v_cvt_pk_bf16_f32 %0, %1, %2" : "=v"(r) : "v"(lo), "v"(hi)); return r;
}

// ---- main kernel: 4 waves x 32 q = 128q/block, 64-kv tiles, 3-buf 1-barrier -
__global__ __launch_bounds__(256, 3) void var_attn17(
    const float* __restrict__ Qg, const float* __restrict__ Kg,
    const float* __restrict__ Vg, float* __restrict__ Og)
{
  const int tid  = threadIdx.x;
  const int lane = tid & 63, wave = tid >> 6;
  const int l15  = lane & 15, lg = lane >> 4;

  // dispatch: bid&7 -> XCD-stable bh-low (L2 reuse); balanced qbi->qb2 map
  int bid  = blockIdx.x;                      // 0..767
  int bhlo = bid & 7;
  int t_   = bid >> 3;                        // 0..95
  int qbi  = t_ >> 4;                         // 0..5
  int bhhi = t_ & 15;
  int qb2  = (qbi == 0) ? 3 : (qbi == 1) ? 5 : (qbi == 2) ? 4
           : (qbi == 3) ? 2 : (qbi == 4) ? 0 : 1;   // nts 11,11,11,7,3,7
  int bh   = bhhi * 8 + bhlo;
  int qblk = qb2 * 128;

  __shared__ short kbuf[3][64 * DHEAD];       // 3 x 8KB, chunk16 ^ (r&7)
  __shared__ short vbuf[3][64 * DHEAD];       // 3 x 8KB, gathered V^T fragments

  const int qw        = qblk + wave * 32;     // wave's 32-q span
  const int q0c       = min(qw + l15,      L_TOK - 1);
  const int q1c       = min(qw + 16 + l15, L_TOK - 1);
  const int kvlen0    = kv_len(q0c);
  const int kvlen1    = kv_len(q1c);
  const int kvmin_w   = kv_len(min(qw, L_TOK - 1));
  const int kv_need_w = (qw < L_TOK) ? kv_len(min(qw + 31, L_TOK - 1)) : 0;
  const int nkv       = kv_len(min(qblk + 127, L_TOK - 1));
  const int nt        = (nkv + 63) >> 6;      // 3,7,7,11,11,11

  // Q fragments for both q-halves, pre-scaled into log2 domain
  s16x8 qf0[2], qf1[2];
  {
    const float* qp0 = Qg + ((size_t)(bh * L_TOK + q0c)) * DHEAD + lg * 8;
    const float* qp1 = Qg + ((size_t)(bh * L_TOK + q1c)) * DHEAD + lg * 8;
    #pragma unroll
    for (int ks = 0; ks < 2; ++ks) {
      f32x4 a0 = *(const f32x4*)(qp0 + ks * 32);
      f32x4 b0 = *(const f32x4*)(qp0 + ks * 32 + 4);
      qf0[ks] = cvt8(a0, b0, SCALE_LOG2);
      f32x4 a1 = *(const f32x4*)(qp1 + ks * 32);
      f32x4 b1 = *(const f32x4*)(qp1 + ks * 32 + 4);
      qf1[ks] = cvt8(a1, b1, SCALE_LOG2);
    }
  }

  const float* kbase = Kg + (size_t)bh * L_TOK * DHEAD;
  const float* vbase = Vg + (size_t)bh * L_TOK * DHEAD;

  // ---- staging thread roles (256 threads per 64x64 tile) ----
  const int kr_s = tid >> 2, kc_s = tid & 3;  // K: row, 16-f32 chunk
  const int vd_s = tid & 63, lg_s = tid >> 6; // V: d, lane-group

  f32x4 kA, kB, kC, kD;   // staged K f32 (single set, rotated schedule)
  float vA[16];           // staged V f32

  auto loadregs = [&](int kt) {
    const int kv0 = kt * 64;
    const float* kp = kbase + (size_t)min(kv0 + kr_s, L_TOK - 1) * DHEAD + kc_s * 16;
    kA = *(const f32x4*)kp;
    kB = *(const f32x4*)(kp + 4);
    kC = *(const f32x4*)(kp + 8);
    kD = *(const f32x4*)(kp + 12);
    #pragma unroll
    for (int f = 0; f < 2; ++f)
      #pragma unroll
      for (int i = 0; i < 4; ++i) {
        int kv = kv0 + f * 32 + lg_s * 4 + i;
        vA[f * 8 + i]     = vbase[(size_t)min(kv,      L_TOK - 1) * DHEAD + vd_s];
        vA[f * 8 + 4 + i] = vbase[(size_t)min(kv + 16, L_TOK - 1) * DHEAD + vd_s];
      }
  };

  auto writelds = [&](int buf) {
    u32x4 k0, k1;
    k0[0] = cvtpk(kA[0], kA[1]); k0[1] = cvtpk(kA[2], kA[3]);
    k0[2] = cvtpk(kB[0], kB[1]); k0[3] = cvtpk(kB[2], kB[3]);
    k1[0] = cvtpk(kC[0], kC[1]); k1[1] = cvtpk(kC[2], kC[3]);
    k1[2] = cvtpk(kD[0], kD[1]); k1[3] = cvtpk(kD[2], kD[3]);
    *(u32x4*)(&kbuf[buf][kr_s * 64 + (((2 * kc_s    ) ^ (kr_s & 7)) * 8)]) = k0;
    *(u32x4*)(&kbuf[buf][kr_s * 64 + (((2 * kc_s + 1) ^ (kr_s & 7)) * 8)]) = k1;
    u32x4 v0, v1;
    v0[0] = cvtpk(vA[0],  vA[1]);  v0[1] = cvtpk(vA[2],  vA[3]);
    v0[2] = cvtpk(vA[4],  vA[5]);  v0[3] = cvtpk(vA[6],  vA[7]);
    v1[0] = cvtpk(vA[8],  vA[9]);  v1[1] = cvtpk(vA[10], vA[11]);
    v1[2] = cvtpk(vA[12], vA[13]); v1[3] = cvtpk(vA[14], vA[15]);
    *(u32x4*)(&vbuf[buf][vd_s * 64 + (((2 * lg_s    ) ^ (vd_s & 7)) * 8)]) = v0;
    *(u32x4*)(&vbuf[buf][vd_s * 64 + (((2 * lg_s + 1) ^ (vd_s & 7)) * 8)]) = v1;
  };

  // hoisted loop-invariant LDS byte offsets (compute phase)
  const int swz   = l15 & 7;
  const int koff0 = l15 * 128 + ((lg    ) ^ swz) * 16;
  const int koff1 = l15 * 128 + ((lg + 4) ^ swz) * 16;
  const int voff0 = l15 * 128 + ((2 * lg    ) ^ swz) * 16;
  const int voff1 = l15 * 128 + ((2 * lg + 1) ^ swz) * 16;

  f32x4 o0[4] = {}, o1[4] = {};
  float l0 = 0.0f, l1 = 0.0f;

  // prologue: stage tile 0 into buf 0; pre-issue tile 1's loads BEFORE barrier
  loadregs(0);
  writelds(0);
  if (nt > 1) loadregs(1);
  __syncthreads();

  int bcur = 0;                               // kt % 3
  for (int kt = 0; kt < nt; ++kt) {
    const int kv0 = kt * 64;
    if (kv0 < kv_need_w) {
      const char* kb = (const char*)&kbuf[bcur][0];
      const char* vb = (const char*)&vbuf[bcur][0];

      // QK^T (swapped): one K read feeds both q-halves
      f32x4 s0a[4], s1a[4];
      #pragma unroll
      for (int t16 = 0; t16 < 4; ++t16) { s0a[t16] = (f32x4)0; s1a[t16] = (f32x4)0; }
      __builtin_amdgcn_s_setprio(1);
      #pragma unroll
      for (int t16 = 0; t16 < 4; ++t16) {
        s16x8 kfa = *(const s16x8*)(kb + t16 * 2048 + koff0);
        s16x8 kfb = *(const s16x8*)(kb + t16 * 2048 + koff1);
        s0a[t16] = __builtin_amdgcn_mfma_f32_16x16x32_bf16(kfa, qf0[0], s0a[t16], 0, 0, 0);
        s0a[t16] = __builtin_amdgcn_mfma_f32_16x16x32_bf16(kfb, qf0[1], s0a[t16], 0, 0, 0);
        s1a[t16] = __builtin_amdgcn_mfma_f32_16x16x32_bf16(kfa, qf1[0], s1a[t16], 0, 0, 0);
        s1a[t16] = __builtin_amdgcn_mfma_f32_16x16x32_bf16(kfb, qf1[1], s1a[t16], 0, 0, 0);
      }
      __builtin_amdgcn_s_setprio(0);

      // fused mask + fixed-max exp2 + sum + cvt_pk, both halves
      u32x4 w00, w01, w10, w11;
      float ls0 = 0.0f, ls1 = 0.0f;
      if (kv0 + 64 <= kvmin_w) {              // wave-uniform full tile
        #pragma unroll
        for (int t16 = 0; t16 < 4; ++t16) {
          float a = exp2f_raw(s0a[t16][0]);
          float b = exp2f_raw(s0a[t16][1]);
          float c = exp2f_raw(s0a[t16][2]);
          float d = exp2f_raw(s0a[t16][3]);
          ls0 += (a + b) + (c + d);
          u32 lo0 = cvtpk(a, b), hi0 = cvtpk(c, d);
          float e = exp2f_raw(s1a[t16][0]);
          float f = exp2f_raw(s1a[t16][1]);
          float g = exp2f_raw(s1a[t16][2]);
          float h = exp2f_raw(s1a[t16][3]);
          ls1 += (e + f) + (g + h);
          u32 lo1 = cvtpk(e, f), hi1 = cvtpk(g, h);
          if (t16 < 2) {
            w00[2 * t16] = lo0; w00[2 * t16 + 1] = hi0;
            w10[2 * t16] = lo1; w10[2 * t16 + 1] = hi1;
          } else {
            w01[2 * (t16 - 2)] = lo0; w01[2 * (t16 - 2) + 1] = hi0;
            w11[2 * (t16 - 2)] = lo1; w11[2 * (t16 - 2) + 1] = hi1;
          }
        }
      } else {
        const int kbq = kv0 + lg * 4;
        #pragma unroll
        for (int t16 = 0; t16 < 4; ++t16) {
          const int k0i = kbq + t16 * 16;
          float a = (k0i     < kvlen0) ? exp2f_raw(s0a[t16][0]) : 0.0f;
          float b = (k0i + 1 < kvlen0) ? exp2f_raw(s0a[t16][1]) : 0.0f;
          float c = (k0i + 2 < kvlen0) ? exp2f_raw(s0a[t16][2]) : 0.0f;
          float d = (k0i + 3 < kvlen0) ? exp2f_raw(s0a[t16][3]) : 0.0f;
          ls0 += (a + b) + (c + d);
          u32 lo0 = cvtpk(a, b), hi0 = cvtpk(c, d);
          float e = (k0i     < kvlen1) ? exp2f_raw(s1a[t16][0]) : 0.0f;
          float f = (k0i + 1 < kvlen1) ? exp2f_raw(s1a[t16][1]) : 0.0f;
          float g = (k0i + 2 < kvlen1) ? exp2f_raw(s1a[t16][2]) : 0.0f;
          float h = (k0i + 3 < kvlen1) ? exp2f_raw(s1a[t16][3]) : 0.0f;
          ls1 += (e + f) + (g + h);
          u32 lo1 = cvtpk(e, f), hi1 = cvtpk(g, h);
          if (t16 < 2) {
            w00[2 * t16] = lo0; w00[2 * t16 + 1] = hi0;
            w10[2 * t16] = lo1; w10[2 * t16 + 1] = hi1;
          } else {
            w01[2 * (t16 - 2)] = lo0; w01[2 * (t16 - 2) + 1] = hi0;
            w11[2 * (t16 - 2)] = lo1; w11[2 * (t16 - 2) + 1] = hi1;
          }
        }
      }
      l0 += ls0;
      l1 += ls1;
      s16x8 pf00 = __builtin_bit_cast(s16x8, w00);
      s16x8 pf01 = __builtin_bit_cast(s16x8, w01);
      s16x8 pf10 = __builtin_bit_cast(s16x8, w10);
      s16x8 pf11 = __builtin_bit_cast(s16x8, w11);

      // PV: one V read feeds both q-halves
      __builtin_amdgcn_s_setprio(1);
      #pragma unroll
      for (int dt = 0; dt < 4; ++dt) {
        s16x8 vf0 = *(const s16x8*)(vb + dt * 2048 + voff0);
        s16x8 vf1 = *(const s16x8*)(vb + dt * 2048 + voff1);
        o0[dt] = __builtin_amdgcn_mfma_f32_16x16x32_bf16(pf00, vf0, o0[dt], 0, 0, 0);
        o0[dt] = __builtin_amdgcn_mfma_f32_16x16x32_bf16(pf01, vf1, o0[dt], 0, 0, 0);
        o1[dt] = __builtin_amdgcn_mfma_f32_16x16x32_bf16(pf10, vf0, o1[dt], 0, 0, 0);
        o1[dt] = __builtin_amdgcn_mfma_f32_16x16x32_bf16(pf11, vf1, o1[dt], 0, 0, 0);
      }
      __builtin_amdgcn_s_setprio(0);
    }

    // rotated staging: write tile kt+1 (regs loaded BEFORE last barrier ->
    // slack = barrier + full compute phase), then immediately issue loads for
    // tile kt+2 into the now-free reg set, THEN barrier.
    if (kt + 1 < nt) {
      int bnext = (bcur == 2) ? 0 : bcur + 1;
      writelds(bnext);                        // buf last read at iter kt-2: safe
      if (kt + 2 < nt) loadregs(kt + 2);
      __syncthreads();
      bcur = bnext;
    }
  }

  // epilogue: reduce l across the 4 replica lane-groups, normalize, store
  l0 += __shfl_xor(l0, 16); l0 += __shfl_xor(l0, 32);
  l1 += __shfl_xor(l1, 16); l1 += __shfl_xor(l1, 32);
  float li0 = 1.0f / l0, li1 = 1.0f / l1;
  float s0q[4], s1q[4];
  #pragma unroll
  for (int r = 0; r < 4; ++r) {
    s0q[r] = __shfl(li0, lg * 4 + r);
    s1q[r] = __shfl(li1, lg * 4 + r);
  }
  #pragma unroll
  for (int r = 0; r < 4; ++r) {
    int qo0 = qw + lg * 4 + r;
    if (qo0 < L_TOK) {
      float* dst = Og + ((size_t)(bh * L_TOK + qo0)) * DHEAD + l15;
      #pragma unroll
      for (int dt = 0; dt < 4; ++dt) dst[dt * 16] = o0[dt][r] * s0q[r];
    }
    int qo1 = qw + 16 + lg * 4 + r;
    if (qo1 < L_TOK) {
      float* dst = Og + ((size_t)(bh * L_TOK + qo1)) * DHEAD + l15;
      #pragma unroll
      for (int dt = 0; dt < 4; ++dt) dst[dt * 16] = o1[dt][r] * s1q[r];
    }
  }
}

extern "C" void kernel_launch(void* const* d_in, const int* in_sizes, int n_in,
                              void* d_out, int out_size, void* d_ws, size_t ws_size,
                              hipStream_t stream) {
  const float* q = (const float*)d_in[0];
  const float* k = (const float*)d_in[1];
  const float* v = (const float*)d_in[2];
  float* o = (float*)d_out;
  (void)d_ws; (void)ws_size;
  var_attn17<<<768, 256, 0, stream>>>(q, k, v, o);
}